// Round 1
// 725.880 us; speedup vs baseline: 1.0601x; 1.0601x over previous
//
#include <hip/hip_runtime.h>
#include <cstdint>
#include <cstddef>

// ---------------------------------------------------------------------------
// GIN forward: h = conv(x; eps0, W1a,W2a) -> conv(h; eps1, W1b,W2b) -> MLP head
// R11: full fp16 pipeline (was bf16). fp16's 2^-11 rel err lets W be a SINGLE
//      fp16 plane (was split bf16 hi/lo) while activations keep the hi/lo
//      split only on the SpMM output Y. Per-block row tile 32 -> 64 (RT=4)
//      to amortize W reads. Net: MLP W L2-traffic 1.6 GB -> 400 MB (4x),
//      GEMM1 3->2 MFMAs/tile, GEMM2 2->1.
// SpMM: per-call CSR build + fp16 multi-edge gather, fp32 accumulate,
//       emitting PRE-SPLIT hi/lo fp16 planes.
// MLP:  fused Linear->ReLU->Linear, 256 thr = 4 waves, 64-row tiles.
//       Hidden tile = ONE fp16 LDS plane [64][264] (33.8 KB -> 4 blocks/CU).
//       launch_bounds(256,3): VGPR cap ~168, guarantees no spill (R10 showed
//       spill is catastrophic: WRITE_SIZE 85->749 MB). If actual VGPR <= 128
//       the HW still gives 4 blocks/CU (LDS-bound).
// ---------------------------------------------------------------------------

using h8  = __attribute__((ext_vector_type(8))) _Float16;       // 8 fp16 = 4 VGPRs
using us8 = __attribute__((ext_vector_type(8))) unsigned short;
using f4  = __attribute__((ext_vector_type(4))) float;          // mfma acc

__device__ inline unsigned short f2h(float f) {   // RNE f32 -> fp16 bits
    _Float16 h = (_Float16)f;
    unsigned short u;
    __builtin_memcpy(&u, &h, 2);
    return u;
}
__device__ inline float h2f(unsigned short u) {
    _Float16 h;
    __builtin_memcpy(&h, &u, 2);
    return (float)h;
}

__global__ __launch_bounds__(256) void k_zero(int* p, int n) {
    int i = blockIdx.x * 256 + threadIdx.x;
    if (i < n) p[i] = 0;
}

__global__ __launch_bounds__(256) void k_hist(const int* __restrict__ row,
                                              int* __restrict__ cnt, int E) {
    int e = blockIdx.x * 256 + threadIdx.x;
    if (e < E) atomicAdd(&cnt[row[e]], 1);
}

// block scans 1024 elements (256 thr x 4); per-element EXCLUSIVE scan within
// block to base, block total to part[b].
__global__ __launch_bounds__(256) void k_scan1(const int* __restrict__ cnt,
                                               int* __restrict__ base,
                                               int* __restrict__ part, int N) {
    __shared__ int sd[256];
    int t = threadIdx.x;
    int i0 = blockIdx.x * 1024 + t * 4;
    int v0 = (i0 + 0 < N) ? cnt[i0 + 0] : 0;
    int v1 = (i0 + 1 < N) ? cnt[i0 + 1] : 0;
    int v2 = (i0 + 2 < N) ? cnt[i0 + 2] : 0;
    int v3 = (i0 + 3 < N) ? cnt[i0 + 3] : 0;
    int ts = v0 + v1 + v2 + v3;
    sd[t] = ts;
    __syncthreads();
    for (int off = 1; off < 256; off <<= 1) {
        int x = (t >= off) ? sd[t - off] : 0;
        __syncthreads();
        sd[t] += x;
        __syncthreads();
    }
    int excl = sd[t] - ts;
    if (i0 + 0 < N) base[i0 + 0] = excl;
    if (i0 + 1 < N) base[i0 + 1] = excl + v0;
    if (i0 + 2 < N) base[i0 + 2] = excl + v0 + v1;
    if (i0 + 3 < N) base[i0 + 3] = excl + v0 + v1 + v2;
    if (t == 255) part[blockIdx.x] = sd[255];
}

__global__ __launch_bounds__(256) void k_scan2(int* part, int NB) {
    __shared__ int sd[256];
    int t = threadIdx.x;
    int v = (t < NB) ? part[t] : 0;
    sd[t] = v;
    __syncthreads();
    for (int off = 1; off < 256; off <<= 1) {
        int x = (t >= off) ? sd[t - off] : 0;
        __syncthreads();
        sd[t] += x;
        __syncthreads();
    }
    if (t < NB) part[t] = sd[t] - v;
}

__global__ __launch_bounds__(256) void k_scan3(int* __restrict__ base,
                                               int* __restrict__ cursor,
                                               const int* __restrict__ part,
                                               int N, int E) {
    int i = blockIdx.x * 256 + threadIdx.x;
    if (i < N) {
        int b = base[i] + part[i >> 10];
        base[i] = b;
        cursor[i] = b;
    }
    if (i == 0) base[N] = E;
}

__global__ __launch_bounds__(256) void k_scatter(const int* __restrict__ row,
                                                 const int* __restrict__ col,
                                                 const float* __restrict__ vals,
                                                 int* __restrict__ cursor,
                                                 int2* __restrict__ edges, int E) {
    int e = blockIdx.x * 256 + threadIdx.x;
    if (e < E) {
        int p = atomicAdd(&cursor[row[e]], 1);
        edges[p] = make_int2(col[e], __float_as_int(vals[e]));
    }
}

// fp32 -> fp16 cast, 4 elems/thread (n divisible by 4)
__global__ __launch_bounds__(256) void k_cvt(const float* __restrict__ x,
                                             unsigned short* __restrict__ xh, int n) {
    int i = (blockIdx.x * 256 + threadIdx.x) * 4;
    if (i < n) {
        float4 v = *(const float4*)(x + i);
        ushort4 o = {f2h(v.x), f2h(v.y), f2h(v.z), f2h(v.w)};
        *(ushort4*)(xh + i) = o;
    }
}

// ---------------------------------------------------------------------------
// Wave-per-node CSR SpMM on fp16 rows, fp32 accumulate, fused eps-residual:
//   Y[i] = (1+eps)*Xh[i] + sum_e val[e] * Xh[col[e]]
// Row = D fp16. L = D/8 lanes cover a row at 16B/lane; R = 64/L edges per
// gather instruction. Butterfly-shfl reduce across edge-parts at the end;
// part 0 adds the self term and stores split fp16 hi/lo planes.
// ---------------------------------------------------------------------------
template <int D>
__global__ __launch_bounds__(256) void k_spmm_h(const int* __restrict__ base,
                                                const int2* __restrict__ edges,
                                                const unsigned short* __restrict__ Xh,
                                                unsigned short* __restrict__ Yhi,
                                                unsigned short* __restrict__ Ylo,
                                                const float* __restrict__ epsp,
                                                int N) {
    constexpr int L = D / 8;    // lanes per row (16 or 32)
    constexpr int R = 64 / L;   // edges per gather instr (4 or 2)
    constexpr int U = 8 / R;    // instrs per inner iter -> 8 edges/iter
    int node = blockIdx.x * 4 + (threadIdx.x >> 6);
    if (node >= N) return;
    const int lane = threadIdx.x & 63;
    const int sub  = lane % L;   // 8-col group within row
    const int part = lane / L;   // which edge of the group
    const float scale = 1.0f + epsp[0];

    float acc[8];
#pragma unroll
    for (int k = 0; k < 8; ++k) acc[k] = 0.0f;

    const int s = base[node];
    const int e = base[node + 1];
    for (int i0 = s; i0 < e; i0 += 64) {
        int rem = e - i0;
        int idx = i0 + (lane < rem ? lane : 0);
        int2 ed = edges[idx];
        int   ci = ed.x;
        float vi = (lane < rem) ? __int_as_float(ed.y) : 0.0f;
        int lim = rem < 64 ? rem : 64;
        for (int j = 0; j < lim; j += 8) {
            int cc[U]; float vv[U];
#pragma unroll
            for (int u = 0; u < U; ++u) {
                int sl = j + u * R + part;      // <= 63 always
                cc[u] = __shfl(ci, sl);
                vv[u] = __shfl(vi, sl);
            }
            h8 g[U];
#pragma unroll
            for (int u = 0; u < U; ++u)
                g[u] = *(const h8*)(Xh + (size_t)cc[u] * D + sub * 8);
#pragma unroll
            for (int u = 0; u < U; ++u)
#pragma unroll
                for (int k = 0; k < 8; ++k)
                    acc[k] = fmaf((float)g[u][k], vv[u], acc[k]);
        }
    }

    // butterfly-reduce across edge parts (lanes L, 2L, ... apart)
#pragma unroll
    for (int st = L; st < 64; st <<= 1)
#pragma unroll
        for (int k = 0; k < 8; ++k)
            acc[k] += __shfl_xor(acc[k], st);

    if (part == 0) {
        h8 xs = *(const h8*)(Xh + (size_t)node * D + sub * 8);
        us8 hi8, lo8;
#pragma unroll
        for (int k = 0; k < 8; ++k) {
            float o = acc[k] + scale * (float)xs[k];
            unsigned short h = f2h(o);
            hi8[k] = h;
            lo8[k] = f2h(o - h2f(h));
        }
        *(us8*)(Yhi + (size_t)node * D + sub * 8) = hi8;
        *(us8*)(Ylo + (size_t)node * D + sub * 8) = lo8;
    }
}

// ---------------------------------------------------------------------------
// W prep: W[M][K] fp32 -> single fp16 plane in exact B-fragment order for
// mfma_f32_16x16x32_f16:
//   Wf[((c*(M/16)+ct)*64 + lane)*8 + j]
// where B[k][n]: n = ct*16 + (lane&15), k = c*32 + (lane>>4)*8 + j.
// ---------------------------------------------------------------------------
__device__ inline void wprep_body(const float* __restrict__ W,
                                  unsigned short* __restrict__ Wf,
                                  int K, int M, int idx) {
    int group = idx >> 9;          // (c, ct); 512 work-items per group
    int r     = idx & 511;
    int lane  = r >> 3;
    int j     = r & 7;
    int c  = group / (M / 16);
    int ct = group - c * (M / 16);
    int n = ct * 16 + (lane & 15);
    int k = c * 32 + (lane >> 4) * 8 + j;
    float w = W[(size_t)n * K + k];
    Wf[(size_t)group * 512 + (size_t)lane * 8 + j] = f2h(w);
}

// one launch preps all six weights; block ranges hardcoded for this problem
__global__ __launch_bounds__(256) void k_wprep_all(
        const float* W1a, unsigned short* Q1a, const float* W2a, unsigned short* Q2a,
        const float* W1b, unsigned short* Q1b, const float* W2b, unsigned short* Q2b,
        const float* Wf1, unsigned short* Qf1, const float* Wf2, unsigned short* Qf2) {
    int b = blockIdx.x;
    const float* W; unsigned short* Q; int K, M, lb;
    if      (b < 128)  { W = W1a; Q = Q1a; K = 128; M = 256; lb = b; }
    else if (b < 384)  { W = W2a; Q = Q2a; K = 256; M = 256; lb = b - 128; }
    else if (b < 640)  { W = W1b; Q = Q1b; K = 256; M = 256; lb = b - 384; }
    else if (b < 896)  { W = W2b; Q = Q2b; K = 256; M = 256; lb = b - 640; }
    else if (b < 1152) { W = Wf1; Q = Qf1; K = 256; M = 256; lb = b - 896; }
    else               { W = Wf2; Q = Qf2; K = 256; M = 64;  lb = b - 1152; }
    wprep_body(W, Q, K, M, lb * 256 + threadIdx.x);
}

// ---------------------------------------------------------------------------
// Fused MLP: C = relu(A @ W1^T + b1) @ W2^T + b2    (A: [N,K], hidden 256,
// out MO). Block = 256 thr = 4 waves; tile = 64 rows x all cols (RT=4
// row-tiles of 16 per wave; each wave owns a 64-col slice in GEMM1).
// ASPLIT: A given as hi/lo fp16 planes (2 MFMAs/tile: Ah*W + Al*W);
//         else single fp16 plane (1 MFMA/tile, exact).
// W is a SINGLE fp16 plane (no lo) -> W traffic per block 256 KB, amortized
// over 64 rows (4x less L2 traffic than the 32-row split-bf16 version).
// Hidden tile = ONE fp16 LDS plane [64][264] (33.8 KB; 4 blocks/CU).
// GEMM2 = 1 MFMA/tile. W pipelined 1-deep with named registers.
// OHALF: output stored fp16 (RNE), else fp32.
// ---------------------------------------------------------------------------
template <int K, int MO, bool ASPLIT, bool OHALF>
__global__ __launch_bounds__(256, 3) void k_mlp(const unsigned short* __restrict__ Ahi,
                                                const unsigned short* __restrict__ Alo,
                                                const unsigned short* __restrict__ Wq1,
                                                const float* __restrict__ b1,
                                                const unsigned short* __restrict__ Wq2,
                                                const float* __restrict__ b2,
                                                void* __restrict__ Cv, int N) {
    constexpr int MH   = 256;
    constexpr int RT   = 4;         // 4 row-tiles of 16 -> 64 rows/block
    constexpr int NCT1 = MH / 64;   // 4 col-tiles per wave (GEMM1)
    constexpr int NCH1 = K / 32;
    constexpr int NCH2 = MH / 32;   // 8
    constexpr int NCT2 = MO / 64 > 0 ? MO / 64 : 1;  // 4 or 1
    constexpr int HS   = 264;       // LDS row stride in halves
    __shared__ unsigned short Hs[64 * HS];

    const int t    = threadIdx.x;
    const int lane = t & 63;
    const int wq   = t >> 6;
    const int r0   = blockIdx.x * 64;
    const int lm   = lane & 15;
    const int lq   = lane >> 4;
    const int kq   = lq * 8;        // k-offset within chunk for this quad

    // A row pointers (fixed across k; clamp: valid mem, clamped rows unused)
    const unsigned short* aph[RT];
    const unsigned short* apl[RT];
#pragma unroll
    for (int rt = 0; rt < RT; ++rt) {
        int gr = r0 + rt * 16 + lm;
        if (gr >= N) gr = N - 1;
        aph[rt] = Ahi + (size_t)gr * K + kq;
        if constexpr (ASPLIT) apl[rt] = Alo + (size_t)gr * K + kq;
    }

    // ---- GEMM1: A @ W1^T -> acc (W pipelined 1-deep) ----
    f4 acc[RT][NCT1];
#pragma unroll
    for (int rt = 0; rt < RT; ++rt)
#pragma unroll
        for (int ct = 0; ct < NCT1; ++ct) acc[rt][ct] = (f4){0.f, 0.f, 0.f, 0.f};

    // W walk: within c: +512 halves per ct; c->c+1: +(16-(NCT1-1))*512
    const unsigned short* wp = Wq1 + ((size_t)(wq * NCT1) * 64 + lane) * 8;
    h8 wh = *(const h8*)(wp);

#pragma unroll 1
    for (int c = 0; c < NCH1; ++c) {
        h8 ah[RT], al[RT];
#pragma unroll
        for (int rt = 0; rt < RT; ++rt) {
            ah[rt] = *(const h8*)(aph[rt] + c * 32);
            if constexpr (ASPLIT) al[rt] = *(const h8*)(apl[rt] + c * 32);
        }
#pragma unroll
        for (int ct = 0; ct < NCT1; ++ct) {
            const unsigned short* wpn = wp + ((ct + 1 < NCT1) ? 512
                                                              : (size_t)(16 - (NCT1 - 1)) * 512);
            h8 whn;
            if (c * NCT1 + ct + 1 < NCH1 * NCT1) whn = *(const h8*)(wpn);
#pragma unroll
            for (int rt = 0; rt < RT; ++rt) {
                acc[rt][ct] = __builtin_amdgcn_mfma_f32_16x16x32_f16(ah[rt], wh, acc[rt][ct], 0, 0, 0);
                if constexpr (ASPLIT)
                    acc[rt][ct] = __builtin_amdgcn_mfma_f32_16x16x32_f16(al[rt], wh, acc[rt][ct], 0, 0, 0);
            }
            wh = whn; wp = wpn;
        }
    }

    // ---- H = relu(acc + b1) -> single fp16 LDS plane ----
#pragma unroll
    for (int ct = 0; ct < NCT1; ++ct) {
        const int col = wq * 64 + ct * 16 + lm;
        const float bv = b1[col];
#pragma unroll
        for (int rt = 0; rt < RT; ++rt) {
#pragma unroll
            for (int reg = 0; reg < 4; ++reg) {
                int rrow = rt * 16 + lq * 4 + reg;
                float v = acc[rt][ct][reg] + bv;
                v = v > 0.f ? v : 0.f;
                Hs[rrow * HS + col] = f2h(v);
            }
        }
    }
    __syncthreads();

    // ---- GEMM2: H @ W2^T + b2 -> C (W pipelined; H from LDS; 1 MFMA/tile) ----
    f4 acc2[RT][NCT2];
#pragma unroll
    for (int rt = 0; rt < RT; ++rt)
#pragma unroll
        for (int ct = 0; ct < NCT2; ++ct) acc2[rt][ct] = (f4){0.f, 0.f, 0.f, 0.f};

    const unsigned short* wp2 = Wq2 + ((size_t)(wq * NCT2) * 64 + lane) * 8;
    h8 wh2 = *(const h8*)(wp2);

#pragma unroll 1
    for (int c = 0; c < NCH2; ++c) {
        const int kk = c * 32 + kq;
        h8 hh[RT];
#pragma unroll
        for (int rt = 0; rt < RT; ++rt)
            hh[rt] = *(const h8*)(Hs + (rt * 16 + lm) * HS + kk);
#pragma unroll
        for (int ct = 0; ct < NCT2; ++ct) {
            const unsigned short* wpn = wp2 + ((ct + 1 < NCT2) ? 512
                                                               : (size_t)(MO / 16 - (NCT2 - 1)) * 512);
            h8 whn;
            if (c * NCT2 + ct + 1 < NCH2 * NCT2) whn = *(const h8*)(wpn);
#pragma unroll
            for (int rt = 0; rt < RT; ++rt)
                acc2[rt][ct] = __builtin_amdgcn_mfma_f32_16x16x32_f16(hh[rt], wh2, acc2[rt][ct], 0, 0, 0);
            wh2 = whn; wp2 = wpn;
        }
    }

#pragma unroll
    for (int ct = 0; ct < NCT2; ++ct) {
        const int col = wq * (MO / 4) + ct * 16 + lm;
        const float bv = b2[col];
#pragma unroll
        for (int rt = 0; rt < RT; ++rt) {
#pragma unroll
            for (int reg = 0; reg < 4; ++reg) {
                int n = r0 + rt * 16 + lq * 4 + reg;
                if (n < N) {
                    float v = acc2[rt][ct][reg] + bv;
                    if constexpr (OHALF)
                        ((unsigned short*)Cv)[(size_t)n * MO + col] = f2h(v);
                    else
                        ((float*)Cv)[(size_t)n * MO + col] = v;
                }
            }
        }
    }
}

extern "C" void kernel_launch(void* const* d_in, const int* in_sizes, int n_in,
                              void* d_out, int out_size, void* d_ws, size_t ws_size,
                              hipStream_t stream) {
    const float* x    = (const float*)d_in[0];
    const int*   row  = (const int*)d_in[1];
    const int*   col  = (const int*)d_in[2];
    const float* vals = (const float*)d_in[3];
    const float* eps0 = (const float*)d_in[4];
    const float* W1a  = (const float*)d_in[5];
    const float* b1a  = (const float*)d_in[6];
    const float* W2a  = (const float*)d_in[7];
    const float* b2a  = (const float*)d_in[8];
    const float* eps1 = (const float*)d_in[9];
    const float* W1b  = (const float*)d_in[10];
    const float* b1b  = (const float*)d_in[11];
    const float* W2b  = (const float*)d_in[12];
    const float* b2b  = (const float*)d_in[13];
    const float* Wf1  = (const float*)d_in[14];
    const float* bf1  = (const float*)d_in[15];
    const float* Wf2  = (const float*)d_in[16];
    const float* bf2  = (const float*)d_in[17];
    float* out = (float*)d_out;

    const int N = in_sizes[0] / 128;  // 100000
    const int E = in_sizes[1];        // 1600000

    char* w = (char*)d_ws;
    auto alloc = [&](size_t bytes) -> void* {
        void* p = (void*)w;
        w += (bytes + 255) & ~(size_t)255;
        return p;
    };
    unsigned short* Yhi    = (unsigned short*)alloc((size_t)N * 256 * 2); // spmm out hi
    unsigned short* Ylo    = (unsigned short*)alloc((size_t)N * 256 * 2); // spmm out lo
    unsigned short* Hb     = (unsigned short*)alloc((size_t)N * 256 * 2); // fp16 activations
    unsigned short* xh     = (unsigned short*)alloc((size_t)N * 128 * 2); // fp16 input copy
    int*            cnt    = (int*)alloc((size_t)N * 4);
    int*            basep  = (int*)alloc((size_t)(N + 1) * 4);
    int*            cursor = (int*)alloc((size_t)N * 4);
    int*            part   = (int*)alloc(1024);
    int2*           edges  = (int2*)alloc((size_t)E * 8);
    unsigned short* Wq1a = (unsigned short*)alloc((size_t)128 * 256 * 2);
    unsigned short* Wq2a = (unsigned short*)alloc((size_t)256 * 256 * 2);
    unsigned short* Wq1b = (unsigned short*)alloc((size_t)256 * 256 * 2);
    unsigned short* Wq2b = (unsigned short*)alloc((size_t)256 * 256 * 2);
    unsigned short* Wqf1 = (unsigned short*)alloc((size_t)256 * 256 * 2);
    unsigned short* Wqf2 = (unsigned short*)alloc((size_t)256 * 64 * 2);

    // ---- CSR build ----
    k_zero<<<(N + 255) / 256, 256, 0, stream>>>(cnt, N);
    k_hist<<<(E + 255) / 256, 256, 0, stream>>>(row, cnt, E);
    int nb = (N + 1023) / 1024;  // 98
    k_scan1<<<nb, 256, 0, stream>>>(cnt, basep, part, N);
    k_scan2<<<1, 256, 0, stream>>>(part, nb);
    k_scan3<<<(N + 255) / 256, 256, 0, stream>>>(basep, cursor, part, N, E);
    k_scatter<<<(E + 255) / 256, 256, 0, stream>>>(row, col, vals, cursor, edges, E);

    // ---- weight fp16 swizzle, input fp16 cast ----
    k_wprep_all<<<1216, 256, 0, stream>>>(W1a, Wq1a, W2a, Wq2a, W1b, Wq1b,
                                          W2b, Wq2b, Wf1, Wqf1, Wf2, Wqf2);
    k_cvt<<<(N * 128 / 4 + 255) / 256, 256, 0, stream>>>(x, xh, N * 128);

    const int mlp_grid  = (N + 63) / 64;
    const int spmm_grid = (N + 3) / 4;

    // ---- conv A ----
    k_spmm_h<128><<<spmm_grid, 256, 0, stream>>>(basep, edges, xh, Yhi, Ylo, eps0, N);
    k_mlp<128, 256, true, true><<<mlp_grid, 256, 0, stream>>>(Yhi, Ylo, Wq1a, b1a, Wq2a, b2a, Hb, N);

    // ---- conv B ----
    k_spmm_h<256><<<spmm_grid, 256, 0, stream>>>(basep, edges, Hb, Yhi, Ylo, eps1, N);
    k_mlp<256, 256, true, true><<<mlp_grid, 256, 0, stream>>>(Yhi, Ylo, Wq1b, b1b, Wq2b, b2b, Hb, N);

    // ---- head (single-plane fp16 A, exact -> 1 MFMA/tile in GEMM1) ----
    k_mlp<256, 64, false, false><<<mlp_grid, 256, 0, stream>>>(Hb, nullptr, Wqf1, bf1, Wqf2, bf2, out, N);
}

// Round 2
// 697.364 us; speedup vs baseline: 1.1035x; 1.0409x over previous
//
#include <hip/hip_runtime.h>
#include <cstdint>
#include <cstddef>

// ---------------------------------------------------------------------------
// GIN forward: h = conv(x; eps0, W1a,W2a) -> conv(h; eps1, W1b,W2b) -> MLP head
// R12: MLP GEMM1 A-staging via async global_load_lds, double-buffered LDS,
//      one barrier per 32-k chunk (minimum 2-phase schedule). A lands in LDS
//      in MFMA-fragment order -> ds_read_b128 at lane*16B, conflict-free.
//      R11 post-mortem: direct global A loads with zero prefetch distance
//      exposed ~900cyc HBM latency per c-iter (MLP ~119us, ~13% MfmaUtil).
// SpMM: unchanged (per-call CSR build + fp16 gather, fp32 accumulate,
//       pre-split hi/lo fp16 planes). ~132us each, L2-miss-path bound.
// MLP:  fused Linear->ReLU->Linear, 256 thr = 4 waves, 64-row tiles.
//       W single fp16 plane (1 MFMA), A hi/lo split (2 MFMAs) in GEMM1.
//       LDS: H plane [64][264] 33.8KB + A dbuf 16KB = 50.2KB -> 3 blocks/CU.
// ---------------------------------------------------------------------------

using h8  = __attribute__((ext_vector_type(8))) _Float16;       // 8 fp16 = 4 VGPRs
using us8 = __attribute__((ext_vector_type(8))) unsigned short;
using f4  = __attribute__((ext_vector_type(4))) float;          // mfma acc

__device__ inline unsigned short f2h(float f) {   // RNE f32 -> fp16 bits
    _Float16 h = (_Float16)f;
    unsigned short u;
    __builtin_memcpy(&u, &h, 2);
    return u;
}
__device__ inline float h2f(unsigned short u) {
    _Float16 h;
    __builtin_memcpy(&h, &u, 2);
    return (float)h;
}

// async 16B/lane global -> LDS. dst must be wave-uniform; HW writes lane i at
// dst + i*16. src is per-lane.
__device__ inline void gl_lds16(const unsigned short* src, unsigned short* dst) {
    __builtin_amdgcn_global_load_lds(
        (const __attribute__((address_space(1))) unsigned int*)src,
        (__attribute__((address_space(3))) unsigned int*)dst, 16, 0, 0);
}

__global__ __launch_bounds__(256) void k_zero(int* p, int n) {
    int i = blockIdx.x * 256 + threadIdx.x;
    if (i < n) p[i] = 0;
}

__global__ __launch_bounds__(256) void k_hist(const int* __restrict__ row,
                                              int* __restrict__ cnt, int E) {
    int e = blockIdx.x * 256 + threadIdx.x;
    if (e < E) atomicAdd(&cnt[row[e]], 1);
}

// block scans 1024 elements (256 thr x 4); per-element EXCLUSIVE scan within
// block to base, block total to part[b].
__global__ __launch_bounds__(256) void k_scan1(const int* __restrict__ cnt,
                                               int* __restrict__ base,
                                               int* __restrict__ part, int N) {
    __shared__ int sd[256];
    int t = threadIdx.x;
    int i0 = blockIdx.x * 1024 + t * 4;
    int v0 = (i0 + 0 < N) ? cnt[i0 + 0] : 0;
    int v1 = (i0 + 1 < N) ? cnt[i0 + 1] : 0;
    int v2 = (i0 + 2 < N) ? cnt[i0 + 2] : 0;
    int v3 = (i0 + 3 < N) ? cnt[i0 + 3] : 0;
    int ts = v0 + v1 + v2 + v3;
    sd[t] = ts;
    __syncthreads();
    for (int off = 1; off < 256; off <<= 1) {
        int x = (t >= off) ? sd[t - off] : 0;
        __syncthreads();
        sd[t] += x;
        __syncthreads();
    }
    int excl = sd[t] - ts;
    if (i0 + 0 < N) base[i0 + 0] = excl;
    if (i0 + 1 < N) base[i0 + 1] = excl + v0;
    if (i0 + 2 < N) base[i0 + 2] = excl + v0 + v1;
    if (i0 + 3 < N) base[i0 + 3] = excl + v0 + v1 + v2;
    if (t == 255) part[blockIdx.x] = sd[255];
}

__global__ __launch_bounds__(256) void k_scan2(int* part, int NB) {
    __shared__ int sd[256];
    int t = threadIdx.x;
    int v = (t < NB) ? part[t] : 0;
    sd[t] = v;
    __syncthreads();
    for (int off = 1; off < 256; off <<= 1) {
        int x = (t >= off) ? sd[t - off] : 0;
        __syncthreads();
        sd[t] += x;
        __syncthreads();
    }
    if (t < NB) part[t] = sd[t] - v;
}

__global__ __launch_bounds__(256) void k_scan3(int* __restrict__ base,
                                               int* __restrict__ cursor,
                                               const int* __restrict__ part,
                                               int N, int E) {
    int i = blockIdx.x * 256 + threadIdx.x;
    if (i < N) {
        int b = base[i] + part[i >> 10];
        base[i] = b;
        cursor[i] = b;
    }
    if (i == 0) base[N] = E;
}

__global__ __launch_bounds__(256) void k_scatter(const int* __restrict__ row,
                                                 const int* __restrict__ col,
                                                 const float* __restrict__ vals,
                                                 int* __restrict__ cursor,
                                                 int2* __restrict__ edges, int E) {
    int e = blockIdx.x * 256 + threadIdx.x;
    if (e < E) {
        int p = atomicAdd(&cursor[row[e]], 1);
        edges[p] = make_int2(col[e], __float_as_int(vals[e]));
    }
}

// fp32 -> fp16 cast, 4 elems/thread (n divisible by 4)
__global__ __launch_bounds__(256) void k_cvt(const float* __restrict__ x,
                                             unsigned short* __restrict__ xh, int n) {
    int i = (blockIdx.x * 256 + threadIdx.x) * 4;
    if (i < n) {
        float4 v = *(const float4*)(x + i);
        ushort4 o = {f2h(v.x), f2h(v.y), f2h(v.z), f2h(v.w)};
        *(ushort4*)(xh + i) = o;
    }
}

// ---------------------------------------------------------------------------
// Wave-per-node CSR SpMM on fp16 rows, fp32 accumulate, fused eps-residual:
//   Y[i] = (1+eps)*Xh[i] + sum_e val[e] * Xh[col[e]]
// ---------------------------------------------------------------------------
template <int D>
__global__ __launch_bounds__(256) void k_spmm_h(const int* __restrict__ base,
                                                const int2* __restrict__ edges,
                                                const unsigned short* __restrict__ Xh,
                                                unsigned short* __restrict__ Yhi,
                                                unsigned short* __restrict__ Ylo,
                                                const float* __restrict__ epsp,
                                                int N) {
    constexpr int L = D / 8;    // lanes per row (16 or 32)
    constexpr int R = 64 / L;   // edges per gather instr (4 or 2)
    constexpr int U = 8 / R;    // instrs per inner iter -> 8 edges/iter
    int node = blockIdx.x * 4 + (threadIdx.x >> 6);
    if (node >= N) return;
    const int lane = threadIdx.x & 63;
    const int sub  = lane % L;   // 8-col group within row
    const int part = lane / L;   // which edge of the group
    const float scale = 1.0f + epsp[0];

    float acc[8];
#pragma unroll
    for (int k = 0; k < 8; ++k) acc[k] = 0.0f;

    const int s = base[node];
    const int e = base[node + 1];
    for (int i0 = s; i0 < e; i0 += 64) {
        int rem = e - i0;
        int idx = i0 + (lane < rem ? lane : 0);
        int2 ed = edges[idx];
        int   ci = ed.x;
        float vi = (lane < rem) ? __int_as_float(ed.y) : 0.0f;
        int lim = rem < 64 ? rem : 64;
        for (int j = 0; j < lim; j += 8) {
            int cc[U]; float vv[U];
#pragma unroll
            for (int u = 0; u < U; ++u) {
                int sl = j + u * R + part;      // <= 63 always
                cc[u] = __shfl(ci, sl);
                vv[u] = __shfl(vi, sl);
            }
            h8 g[U];
#pragma unroll
            for (int u = 0; u < U; ++u)
                g[u] = *(const h8*)(Xh + (size_t)cc[u] * D + sub * 8);
#pragma unroll
            for (int u = 0; u < U; ++u)
#pragma unroll
                for (int k = 0; k < 8; ++k)
                    acc[k] = fmaf((float)g[u][k], vv[u], acc[k]);
        }
    }

    // butterfly-reduce across edge parts (lanes L, 2L, ... apart)
#pragma unroll
    for (int st = L; st < 64; st <<= 1)
#pragma unroll
        for (int k = 0; k < 8; ++k)
            acc[k] += __shfl_xor(acc[k], st);

    if (part == 0) {
        h8 xs = *(const h8*)(Xh + (size_t)node * D + sub * 8);
        us8 hi8, lo8;
#pragma unroll
        for (int k = 0; k < 8; ++k) {
            float o = acc[k] + scale * (float)xs[k];
            unsigned short h = f2h(o);
            hi8[k] = h;
            lo8[k] = f2h(o - h2f(h));
        }
        *(us8*)(Yhi + (size_t)node * D + sub * 8) = hi8;
        *(us8*)(Ylo + (size_t)node * D + sub * 8) = lo8;
    }
}

// ---------------------------------------------------------------------------
// W prep: W[M][K] fp32 -> single fp16 plane in exact B-fragment order for
// mfma_f32_16x16x32_f16:
//   Wf[((c*(M/16)+ct)*64 + lane)*8 + j]
// where B[k][n]: n = ct*16 + (lane&15), k = c*32 + (lane>>4)*8 + j.
// ---------------------------------------------------------------------------
__device__ inline void wprep_body(const float* __restrict__ W,
                                  unsigned short* __restrict__ Wf,
                                  int K, int M, int idx) {
    int group = idx >> 9;          // (c, ct); 512 work-items per group
    int r     = idx & 511;
    int lane  = r >> 3;
    int j     = r & 7;
    int c  = group / (M / 16);
    int ct = group - c * (M / 16);
    int n = ct * 16 + (lane & 15);
    int k = c * 32 + (lane >> 4) * 8 + j;
    float w = W[(size_t)n * K + k];
    Wf[(size_t)group * 512 + (size_t)lane * 8 + j] = f2h(w);
}

// one launch preps all six weights; block ranges hardcoded for this problem
__global__ __launch_bounds__(256) void k_wprep_all(
        const float* W1a, unsigned short* Q1a, const float* W2a, unsigned short* Q2a,
        const float* W1b, unsigned short* Q1b, const float* W2b, unsigned short* Q2b,
        const float* Wf1, unsigned short* Qf1, const float* Wf2, unsigned short* Qf2) {
    int b = blockIdx.x;
    const float* W; unsigned short* Q; int K, M, lb;
    if      (b < 128)  { W = W1a; Q = Q1a; K = 128; M = 256; lb = b; }
    else if (b < 384)  { W = W2a; Q = Q2a; K = 256; M = 256; lb = b - 128; }
    else if (b < 640)  { W = W1b; Q = Q1b; K = 256; M = 256; lb = b - 384; }
    else if (b < 896)  { W = W2b; Q = Q2b; K = 256; M = 256; lb = b - 640; }
    else if (b < 1152) { W = Wf1; Q = Qf1; K = 256; M = 256; lb = b - 896; }
    else               { W = Wf2; Q = Qf2; K = 256; M = 64;  lb = b - 1152; }
    wprep_body(W, Q, K, M, lb * 256 + threadIdx.x);
}

// ---------------------------------------------------------------------------
// Fused MLP: C = relu(A @ W1^T + b1) @ W2^T + b2    (A: [N,K], hidden 256,
// out MO). Block = 256 thr = 4 waves; tile = 64 rows (RT=4 row-tiles of 16
// per wave; each wave owns a 64-col slice in GEMM1).
//
// GEMM1 A-path (NEW): per 32-k chunk c, wave w async-stages ITS 16 rows
// (rows r0+w*16 .. +15) x 32 k x PL planes into LDS via global_load_lds,
// double-buffered. LDS layout is fragment order:
//   Ab[buf][plane][rt*512 + lane*8]  (halves)   -> stage dest for wave w is
// the wave-uniform base Ab+...+w*512 (HW writes lane i at +i*16B); frag read
// back is ds_read_b128 at lane*16B: conflict-free.
// Schedule per c: issue stage(c+1) -> ds_read frags(c) -> MFMAs -> barrier
// (drains vmcnt so buf^1 is ready and all waves are past buf's reads).
//
// ASPLIT: A as hi/lo fp16 planes (2 MFMAs/tile); else single plane (1 MFMA).
// W single fp16 plane, register-pipelined 1-deep (L2-resident).
// Hidden tile = ONE fp16 LDS plane [64][264]. GEMM2 = 1 MFMA/tile.
// LDS total: 33.8K (H) + 16K (A dbuf, split) = 50.2KB -> 3 blocks/CU.
// OHALF: output stored fp16 (RNE), else fp32.
// ---------------------------------------------------------------------------
template <int K, int MO, bool ASPLIT, bool OHALF>
__global__ __launch_bounds__(256, 3) void k_mlp(const unsigned short* __restrict__ Ahi,
                                                const unsigned short* __restrict__ Alo,
                                                const unsigned short* __restrict__ Wq1,
                                                const float* __restrict__ b1,
                                                const unsigned short* __restrict__ Wq2,
                                                const float* __restrict__ b2,
                                                void* __restrict__ Cv, int N) {
    constexpr int MH   = 256;
    constexpr int RT   = 4;         // 4 row-tiles of 16 -> 64 rows/block
    constexpr int NCT1 = MH / 64;   // 4 col-tiles per wave (GEMM1)
    constexpr int NCH1 = K / 32;
    constexpr int NCH2 = MH / 32;   // 8
    constexpr int NCT2 = MO / 64 > 0 ? MO / 64 : 1;  // 4 or 1
    constexpr int HS   = 264;       // LDS row stride in halves
    constexpr int PL   = ASPLIT ? 2 : 1;
    __shared__ unsigned short Hs[64 * HS];
    __shared__ unsigned short Ab[2 * PL * 2048];   // [buf][plane][4 rt][64 ln][8]

    const int t    = threadIdx.x;
    const int lane = t & 63;
    const int wq   = t >> 6;
    const int r0   = blockIdx.x * 64;
    const int lm   = lane & 15;
    const int lq   = lane >> 4;
    const int kq   = lq * 8;        // k-offset within chunk for this quad

    // global A source for staging: wave w stages rows r0+w*16+lm, k = c*32+kq
    int gr = r0 + wq * 16 + lm;
    if (gr >= N) gr = N - 1;        // clamp: valid mem; clamped rows unused
    const unsigned short* gAh = Ahi + (size_t)gr * K + kq;
    const unsigned short* gAl = nullptr;
    if constexpr (ASPLIT) gAl = Alo + (size_t)gr * K + kq;

    // ---- GEMM1: A @ W1^T -> acc ----
    f4 acc[RT][NCT1];
#pragma unroll
    for (int rt = 0; rt < RT; ++rt)
#pragma unroll
        for (int ct = 0; ct < NCT1; ++ct) acc[rt][ct] = (f4){0.f, 0.f, 0.f, 0.f};

    // W walk: within c: +512 halves per ct; c->c+1: +(16-(NCT1-1))*512
    const unsigned short* wp = Wq1 + ((size_t)(wq * NCT1) * 64 + lane) * 8;
    h8 wh = *(const h8*)(wp);

    // prologue: stage chunk 0 into buf 0
    {
        unsigned short* d = Ab + wq * 512;
        gl_lds16(gAh, d);
        if constexpr (ASPLIT) gl_lds16(gAl, d + 2048);
    }
    __syncthreads();

    int cur = 0;
#pragma unroll 1
    for (int c = 0; c < NCH1; ++c) {
        // issue async stage of chunk c+1 into the other buffer
        if (c + 1 < NCH1) {
            unsigned short* d = Ab + (cur ^ 1) * (PL * 2048) + wq * 512;
            gl_lds16(gAh + (c + 1) * 32, d);
            if constexpr (ASPLIT) gl_lds16(gAl + (c + 1) * 32, d + 2048);
        }
        // A fragments from LDS (lane-linear b128, conflict-free)
        const unsigned short* ab = Ab + cur * (PL * 2048);
        h8 ah[RT], al[RT];
#pragma unroll
        for (int rt = 0; rt < RT; ++rt) {
            ah[rt] = *(const h8*)(ab + rt * 512 + lane * 8);
            if constexpr (ASPLIT) al[rt] = *(const h8*)(ab + 2048 + rt * 512 + lane * 8);
        }
#pragma unroll
        for (int ct = 0; ct < NCT1; ++ct) {
            const unsigned short* wpn = wp + ((ct + 1 < NCT1) ? 512
                                                              : (size_t)(16 - (NCT1 - 1)) * 512);
            h8 whn;
            if (c * NCT1 + ct + 1 < NCH1 * NCT1) whn = *(const h8*)(wpn);
#pragma unroll
            for (int rt = 0; rt < RT; ++rt) {
                acc[rt][ct] = __builtin_amdgcn_mfma_f32_16x16x32_f16(ah[rt], wh, acc[rt][ct], 0, 0, 0);
                if constexpr (ASPLIT)
                    acc[rt][ct] = __builtin_amdgcn_mfma_f32_16x16x32_f16(al[rt], wh, acc[rt][ct], 0, 0, 0);
            }
            wh = whn; wp = wpn;
        }
        // drains vmcnt (stage c+1 landed) + lgkm; all waves past buf[cur] reads
        __syncthreads();
        cur ^= 1;
    }

    // ---- H = relu(acc + b1) -> single fp16 LDS plane ----
#pragma unroll
    for (int ct = 0; ct < NCT1; ++ct) {
        const int col = wq * 64 + ct * 16 + lm;
        const float bv = b1[col];
#pragma unroll
        for (int rt = 0; rt < RT; ++rt) {
#pragma unroll
            for (int reg = 0; reg < 4; ++reg) {
                int rrow = rt * 16 + lq * 4 + reg;
                float v = acc[rt][ct][reg] + bv;
                v = v > 0.f ? v : 0.f;
                Hs[rrow * HS + col] = f2h(v);
            }
        }
    }
    __syncthreads();

    // ---- GEMM2: H @ W2^T + b2 -> C (W pipelined; H from LDS; 1 MFMA/tile) ----
    f4 acc2[RT][NCT2];
#pragma unroll
    for (int rt = 0; rt < RT; ++rt)
#pragma unroll
        for (int ct = 0; ct < NCT2; ++ct) acc2[rt][ct] = (f4){0.f, 0.f, 0.f, 0.f};

    const unsigned short* wp2 = Wq2 + ((size_t)(wq * NCT2) * 64 + lane) * 8;
    h8 wh2 = *(const h8*)(wp2);

#pragma unroll 1
    for (int c = 0; c < NCH2; ++c) {
        const int kk = c * 32 + kq;
        h8 hh[RT];
#pragma unroll
        for (int rt = 0; rt < RT; ++rt)
            hh[rt] = *(const h8*)(Hs + (rt * 16 + lm) * HS + kk);
#pragma unroll
        for (int ct = 0; ct < NCT2; ++ct) {
            const unsigned short* wpn = wp2 + ((ct + 1 < NCT2) ? 512
                                                               : (size_t)(MO / 16 - (NCT2 - 1)) * 512);
            h8 whn;
            if (c * NCT2 + ct + 1 < NCH2 * NCT2) whn = *(const h8*)(wpn);
#pragma unroll
            for (int rt = 0; rt < RT; ++rt)
                acc2[rt][ct] = __builtin_amdgcn_mfma_f32_16x16x32_f16(hh[rt], wh2, acc2[rt][ct], 0, 0, 0);
            wh2 = whn; wp2 = wpn;
        }
    }

#pragma unroll
    for (int ct = 0; ct < NCT2; ++ct) {
        const int col = wq * (MO / 4) + ct * 16 + lm;
        const float bv = b2[col];
#pragma unroll
        for (int rt = 0; rt < RT; ++rt) {
#pragma unroll
            for (int reg = 0; reg < 4; ++reg) {
                int n = r0 + rt * 16 + lq * 4 + reg;
                if (n < N) {
                    float v = acc2[rt][ct][reg] + bv;
                    if constexpr (OHALF)
                        ((unsigned short*)Cv)[(size_t)n * MO + col] = f2h(v);
                    else
                        ((float*)Cv)[(size_t)n * MO + col] = v;
                }
            }
        }
    }
}

extern "C" void kernel_launch(void* const* d_in, const int* in_sizes, int n_in,
                              void* d_out, int out_size, void* d_ws, size_t ws_size,
                              hipStream_t stream) {
    const float* x    = (const float*)d_in[0];
    const int*   row  = (const int*)d_in[1];
    const int*   col  = (const int*)d_in[2];
    const float* vals = (const float*)d_in[3];
    const float* eps0 = (const float*)d_in[4];
    const float* W1a  = (const float*)d_in[5];
    const float* b1a  = (const float*)d_in[6];
    const float* W2a  = (const float*)d_in[7];
    const float* b2a  = (const float*)d_in[8];
    const float* eps1 = (const float*)d_in[9];
    const float* W1b  = (const float*)d_in[10];
    const float* b1b  = (const float*)d_in[11];
    const float* W2b  = (const float*)d_in[12];
    const float* b2b  = (const float*)d_in[13];
    const float* Wf1  = (const float*)d_in[14];
    const float* bf1  = (const float*)d_in[15];
    const float* Wf2  = (const float*)d_in[16];
    const float* bf2  = (const float*)d_in[17];
    float* out = (float*)d_out;

    const int N = in_sizes[0] / 128;  // 100000
    const int E = in_sizes[1];        // 1600000

    char* w = (char*)d_ws;
    auto alloc = [&](size_t bytes) -> void* {
        void* p = (void*)w;
        w += (bytes + 255) & ~(size_t)255;
        return p;
    };
    unsigned short* Yhi    = (unsigned short*)alloc((size_t)N * 256 * 2); // spmm out hi
    unsigned short* Ylo    = (unsigned short*)alloc((size_t)N * 256 * 2); // spmm out lo
    unsigned short* Hb     = (unsigned short*)alloc((size_t)N * 256 * 2); // fp16 activations
    unsigned short* xh     = (unsigned short*)alloc((size_t)N * 128 * 2); // fp16 input copy
    int*            cnt    = (int*)alloc((size_t)N * 4);
    int*            basep  = (int*)alloc((size_t)(N + 1) * 4);
    int*            cursor = (int*)alloc((size_t)N * 4);
    int*            part   = (int*)alloc(1024);
    int2*           edges  = (int2*)alloc((size_t)E * 8);
    unsigned short* Wq1a = (unsigned short*)alloc((size_t)128 * 256 * 2);
    unsigned short* Wq2a = (unsigned short*)alloc((size_t)256 * 256 * 2);
    unsigned short* Wq1b = (unsigned short*)alloc((size_t)256 * 256 * 2);
    unsigned short* Wq2b = (unsigned short*)alloc((size_t)256 * 256 * 2);
    unsigned short* Wqf1 = (unsigned short*)alloc((size_t)256 * 256 * 2);
    unsigned short* Wqf2 = (unsigned short*)alloc((size_t)256 * 64 * 2);

    // ---- CSR build ----
    k_zero<<<(N + 255) / 256, 256, 0, stream>>>(cnt, N);
    k_hist<<<(E + 255) / 256, 256, 0, stream>>>(row, cnt, E);
    int nb = (N + 1023) / 1024;  // 98
    k_scan1<<<nb, 256, 0, stream>>>(cnt, basep, part, N);
    k_scan2<<<1, 256, 0, stream>>>(part, nb);
    k_scan3<<<(N + 255) / 256, 256, 0, stream>>>(basep, cursor, part, N, E);
    k_scatter<<<(E + 255) / 256, 256, 0, stream>>>(row, col, vals, cursor, edges, E);

    // ---- weight fp16 swizzle, input fp16 cast ----
    k_wprep_all<<<1216, 256, 0, stream>>>(W1a, Wq1a, W2a, Wq2a, W1b, Wq1b,
                                          W2b, Wq2b, Wf1, Wqf1, Wf2, Wqf2);
    k_cvt<<<(N * 128 / 4 + 255) / 256, 256, 0, stream>>>(x, xh, N * 128);

    const int mlp_grid  = (N + 63) / 64;
    const int spmm_grid = (N + 3) / 4;

    // ---- conv A ----
    k_spmm_h<128><<<spmm_grid, 256, 0, stream>>>(basep, edges, xh, Yhi, Ylo, eps0, N);
    k_mlp<128, 256, true, true><<<mlp_grid, 256, 0, stream>>>(Yhi, Ylo, Wq1a, b1a, Wq2a, b2a, Hb, N);

    // ---- conv B ----
    k_spmm_h<256><<<spmm_grid, 256, 0, stream>>>(basep, edges, Hb, Yhi, Ylo, eps1, N);
    k_mlp<256, 256, true, true><<<mlp_grid, 256, 0, stream>>>(Yhi, Ylo, Wq1b, b1b, Wq2b, b2b, Hb, N);

    // ---- head (single-plane fp16 A, exact -> 1 MFMA/tile in GEMM1) ----
    k_mlp<256, 64, false, false><<<mlp_grid, 256, 0, stream>>>(Hb, nullptr, Wqf1, bf1, Wqf2, bf2, out, N);
}

// Round 3
// 643.548 us; speedup vs baseline: 1.1958x; 1.0836x over previous
//
#include <hip/hip_runtime.h>
#include <cstdint>
#include <cstddef>

// ---------------------------------------------------------------------------
// GIN forward: h = conv(x; eps0, W1a,W2a) -> conv(h; eps1, W1b,W2b) -> MLP head
// R13: (a) single fp16 Y plane (dropped hi/lo split): halves GEMM1 MFMA work,
//      A-stage bytes, and SpMM write traffic. Error budget ~5e-4/unit, same
//      order as existing fp16 H/W quant terms.
//      (b) counted-vmcnt ring-4 A staging (T3+T4): raw s_barrier (no vmcnt
//      drain), s_waitcnt vmcnt(N) with exact per-phase constants, stage(c)
//      issued 3 phases (~900+cyc) ahead; W register-prefetched one full
//      phase (~300cyc) ahead of use (covers L2 ~200cyc).
//      R12 post-mortem: __syncthreads' vmcnt(0) drain exposed HBM latency
//      every phase; W 1-ct-deep prefetch exposed ~150cyc L2 stall per ct.
// MLP:  256 thr = 4 waves, 64-row tiles. LDS: H [64][264] 33.8KB + A ring
//      4x4KB = 49.8KB -> 3 blocks/CU.
// ---------------------------------------------------------------------------

using h8  = __attribute__((ext_vector_type(8))) _Float16;       // 8 fp16 = 4 VGPRs
using us8 = __attribute__((ext_vector_type(8))) unsigned short;
using f4  = __attribute__((ext_vector_type(4))) float;          // mfma acc

__device__ inline unsigned short f2h(float f) {   // RNE f32 -> fp16 bits
    _Float16 h = (_Float16)f;
    unsigned short u;
    __builtin_memcpy(&u, &h, 2);
    return u;
}

// async 16B/lane global -> LDS. dst wave-uniform; HW writes lane i at +i*16.
__device__ inline void gl_lds16(const unsigned short* src, unsigned short* dst) {
    __builtin_amdgcn_global_load_lds(
        (const __attribute__((address_space(1))) unsigned int*)src,
        (__attribute__((address_space(3))) unsigned int*)dst, 16, 0, 0);
}

// counted vmcnt wait; n is compile-time-folded after full unroll.
__device__ __forceinline__ void waitvn(int n) {
    switch (n) {
    case 0:  asm volatile("s_waitcnt vmcnt(0)" ::: "memory"); break;
    case 2:  asm volatile("s_waitcnt vmcnt(2)" ::: "memory"); break;
    case 6:  asm volatile("s_waitcnt vmcnt(6)" ::: "memory"); break;
    case 8:  asm volatile("s_waitcnt vmcnt(8)" ::: "memory"); break;
    case 9:  asm volatile("s_waitcnt vmcnt(9)" ::: "memory"); break;
    case 10: asm volatile("s_waitcnt vmcnt(10)" ::: "memory"); break;
    default: asm volatile("s_waitcnt vmcnt(0)" ::: "memory"); break;
    }
}

__global__ __launch_bounds__(256) void k_zero(int* p, int n) {
    int i = blockIdx.x * 256 + threadIdx.x;
    if (i < n) p[i] = 0;
}

__global__ __launch_bounds__(256) void k_hist(const int* __restrict__ row,
                                              int* __restrict__ cnt, int E) {
    int e = blockIdx.x * 256 + threadIdx.x;
    if (e < E) atomicAdd(&cnt[row[e]], 1);
}

__global__ __launch_bounds__(256) void k_scan1(const int* __restrict__ cnt,
                                               int* __restrict__ base,
                                               int* __restrict__ part, int N) {
    __shared__ int sd[256];
    int t = threadIdx.x;
    int i0 = blockIdx.x * 1024 + t * 4;
    int v0 = (i0 + 0 < N) ? cnt[i0 + 0] : 0;
    int v1 = (i0 + 1 < N) ? cnt[i0 + 1] : 0;
    int v2 = (i0 + 2 < N) ? cnt[i0 + 2] : 0;
    int v3 = (i0 + 3 < N) ? cnt[i0 + 3] : 0;
    int ts = v0 + v1 + v2 + v3;
    sd[t] = ts;
    __syncthreads();
    for (int off = 1; off < 256; off <<= 1) {
        int x = (t >= off) ? sd[t - off] : 0;
        __syncthreads();
        sd[t] += x;
        __syncthreads();
    }
    int excl = sd[t] - ts;
    if (i0 + 0 < N) base[i0 + 0] = excl;
    if (i0 + 1 < N) base[i0 + 1] = excl + v0;
    if (i0 + 2 < N) base[i0 + 2] = excl + v0 + v1;
    if (i0 + 3 < N) base[i0 + 3] = excl + v0 + v1 + v2;
    if (t == 255) part[blockIdx.x] = sd[255];
}

__global__ __launch_bounds__(256) void k_scan2(int* part, int NB) {
    __shared__ int sd[256];
    int t = threadIdx.x;
    int v = (t < NB) ? part[t] : 0;
    sd[t] = v;
    __syncthreads();
    for (int off = 1; off < 256; off <<= 1) {
        int x = (t >= off) ? sd[t - off] : 0;
        __syncthreads();
        sd[t] += x;
        __syncthreads();
    }
    if (t < NB) part[t] = sd[t] - v;
}

__global__ __launch_bounds__(256) void k_scan3(int* __restrict__ base,
                                               int* __restrict__ cursor,
                                               const int* __restrict__ part,
                                               int N, int E) {
    int i = blockIdx.x * 256 + threadIdx.x;
    if (i < N) {
        int b = base[i] + part[i >> 10];
        base[i] = b;
        cursor[i] = b;
    }
    if (i == 0) base[N] = E;
}

__global__ __launch_bounds__(256) void k_scatter(const int* __restrict__ row,
                                                 const int* __restrict__ col,
                                                 const float* __restrict__ vals,
                                                 int* __restrict__ cursor,
                                                 int2* __restrict__ edges, int E) {
    int e = blockIdx.x * 256 + threadIdx.x;
    if (e < E) {
        int p = atomicAdd(&cursor[row[e]], 1);
        edges[p] = make_int2(col[e], __float_as_int(vals[e]));
    }
}

// fp32 -> fp16 cast, 4 elems/thread (n divisible by 4)
__global__ __launch_bounds__(256) void k_cvt(const float* __restrict__ x,
                                             unsigned short* __restrict__ xh, int n) {
    int i = (blockIdx.x * 256 + threadIdx.x) * 4;
    if (i < n) {
        float4 v = *(const float4*)(x + i);
        ushort4 o = {f2h(v.x), f2h(v.y), f2h(v.z), f2h(v.w)};
        *(ushort4*)(xh + i) = o;
    }
}

// ---------------------------------------------------------------------------
// Wave-per-node CSR SpMM on fp16 rows, fp32 accumulate, fused eps-residual:
//   Y[i] = (1+eps)*Xh[i] + sum_e val[e] * Xh[col[e]]   (single fp16 output)
// ---------------------------------------------------------------------------
template <int D>
__global__ __launch_bounds__(256) void k_spmm_h(const int* __restrict__ base,
                                                const int2* __restrict__ edges,
                                                const unsigned short* __restrict__ Xh,
                                                unsigned short* __restrict__ Y,
                                                const float* __restrict__ epsp,
                                                int N) {
    constexpr int L = D / 8;    // lanes per row (16 or 32)
    constexpr int R = 64 / L;   // edges per gather instr (4 or 2)
    constexpr int U = 8 / R;    // instrs per inner iter -> 8 edges/iter
    int node = blockIdx.x * 4 + (threadIdx.x >> 6);
    if (node >= N) return;
    const int lane = threadIdx.x & 63;
    const int sub  = lane % L;   // 8-col group within row
    const int part = lane / L;   // which edge of the group
    const float scale = 1.0f + epsp[0];

    float acc[8];
#pragma unroll
    for (int k = 0; k < 8; ++k) acc[k] = 0.0f;

    const int s = base[node];
    const int e = base[node + 1];
    for (int i0 = s; i0 < e; i0 += 64) {
        int rem = e - i0;
        int idx = i0 + (lane < rem ? lane : 0);
        int2 ed = edges[idx];
        int   ci = ed.x;
        float vi = (lane < rem) ? __int_as_float(ed.y) : 0.0f;
        int lim = rem < 64 ? rem : 64;
        for (int j = 0; j < lim; j += 8) {
            int cc[U]; float vv[U];
#pragma unroll
            for (int u = 0; u < U; ++u) {
                int sl = j + u * R + part;      // <= 63 always
                cc[u] = __shfl(ci, sl);
                vv[u] = __shfl(vi, sl);
            }
            h8 g[U];
#pragma unroll
            for (int u = 0; u < U; ++u)
                g[u] = *(const h8*)(Xh + (size_t)cc[u] * D + sub * 8);
#pragma unroll
            for (int u = 0; u < U; ++u)
#pragma unroll
                for (int k = 0; k < 8; ++k)
                    acc[k] = fmaf((float)g[u][k], vv[u], acc[k]);
        }
    }

    // butterfly-reduce across edge parts (lanes L, 2L, ... apart)
#pragma unroll
    for (int st = L; st < 64; st <<= 1)
#pragma unroll
        for (int k = 0; k < 8; ++k)
            acc[k] += __shfl_xor(acc[k], st);

    if (part == 0) {
        h8 xs = *(const h8*)(Xh + (size_t)node * D + sub * 8);
        us8 hi8;
#pragma unroll
        for (int k = 0; k < 8; ++k)
            hi8[k] = f2h(acc[k] + scale * (float)xs[k]);
        *(us8*)(Y + (size_t)node * D + sub * 8) = hi8;
    }
}

// ---------------------------------------------------------------------------
// W prep: W[M][K] fp32 -> single fp16 plane in exact B-fragment order for
// mfma_f32_16x16x32_f16:
//   Wf[((c*(M/16)+ct)*64 + lane)*8 + j]
// where B[k][n]: n = ct*16 + (lane&15), k = c*32 + (lane>>4)*8 + j.
// ---------------------------------------------------------------------------
__device__ inline void wprep_body(const float* __restrict__ W,
                                  unsigned short* __restrict__ Wf,
                                  int K, int M, int idx) {
    int group = idx >> 9;          // (c, ct); 512 work-items per group
    int r     = idx & 511;
    int lane  = r >> 3;
    int j     = r & 7;
    int c  = group / (M / 16);
    int ct = group - c * (M / 16);
    int n = ct * 16 + (lane & 15);
    int k = c * 32 + (lane >> 4) * 8 + j;
    float w = W[(size_t)n * K + k];
    Wf[(size_t)group * 512 + (size_t)lane * 8 + j] = f2h(w);
}

__global__ __launch_bounds__(256) void k_wprep_all(
        const float* W1a, unsigned short* Q1a, const float* W2a, unsigned short* Q2a,
        const float* W1b, unsigned short* Q1b, const float* W2b, unsigned short* Q2b,
        const float* Wf1, unsigned short* Qf1, const float* Wf2, unsigned short* Qf2) {
    int b = blockIdx.x;
    const float* W; unsigned short* Q; int K, M, lb;
    if      (b < 128)  { W = W1a; Q = Q1a; K = 128; M = 256; lb = b; }
    else if (b < 384)  { W = W2a; Q = Q2a; K = 256; M = 256; lb = b - 128; }
    else if (b < 640)  { W = W1b; Q = Q1b; K = 256; M = 256; lb = b - 384; }
    else if (b < 896)  { W = W2b; Q = Q2b; K = 256; M = 256; lb = b - 640; }
    else if (b < 1152) { W = Wf1; Q = Qf1; K = 256; M = 256; lb = b - 896; }
    else               { W = Wf2; Q = Qf2; K = 256; M = 64;  lb = b - 1152; }
    wprep_body(W, Q, K, M, lb * 256 + threadIdx.x);
}

// ---------------------------------------------------------------------------
// Fused MLP: C = relu(A @ W1^T + b1) @ W2^T + b2    (A: [N,K] fp16, hidden
// 256, out MO). Block = 256 thr = 4 waves; tile = 64 rows.
//
// GEMM1 pipeline (counted vmcnt, ring-4):
//   phase c: waitvn(Nc)            -- own stage(c) landed (issued 3 phases ago)
//            s_barrier (raw)       -- ALL waves' stage(c) landed; all done
//                                     reading ring[(c-1)&3] (overwritten next)
//            load Wset(c+1) (4xb128, L2, used next phase ~300cyc later)
//            stage(c+3) (global_load_lds, HBM, used 3 phases later)
//            ds_read A frags (lane-linear b128, conflict-free); 16 MFMA
//   Nc = #vmem issued after stage(c) in program order (exact per-phase
//   constants; any compiler sinking only makes the wait stronger).
// GEMM2: H from LDS, Wset2 register-prefetched 1 phase ahead. No barriers.
// LDS: H [64][264] 33.8KB + A ring 4x4KB = 49.8KB -> 3 blocks/CU.
// ---------------------------------------------------------------------------
template <int K, int MO, bool OHALF>
__global__ __launch_bounds__(256, 3) void k_mlp(const unsigned short* __restrict__ A,
                                                const unsigned short* __restrict__ Wq1,
                                                const float* __restrict__ b1,
                                                const unsigned short* __restrict__ Wq2,
                                                const float* __restrict__ b2,
                                                void* __restrict__ Cv, int N) {
    constexpr int MH   = 256;
    constexpr int RT   = 4;         // 4 row-tiles of 16 -> 64 rows/block
    constexpr int NCT1 = MH / 64;   // 4 col-tiles per wave (GEMM1)
    constexpr int NCH1 = K / 32;    // 4 or 8
    constexpr int NCH2 = MH / 32;   // 8
    constexpr int NCT2 = MO / 64 > 0 ? MO / 64 : 1;  // 4 or 1
    constexpr int HS   = 264;       // LDS row stride in halves
    __shared__ unsigned short Hs[64 * HS];
    __shared__ unsigned short Ab[4 * 2048];   // ring: [buf][4 rt][64 ln][8]

    const int t    = threadIdx.x;
    const int lane = t & 63;
    const int wq   = t >> 6;
    const int r0   = blockIdx.x * 64;
    const int lm   = lane & 15;
    const int lq   = lane >> 4;
    const int kq   = lq * 8;        // k-offset within chunk for this quad

    // global A source for staging: wave w stages rows r0+w*16+lm, k = c*32+kq
    int gr = r0 + wq * 16 + lm;
    if (gr >= N) gr = N - 1;        // clamp: valid mem; clamped rows unused
    const unsigned short* gA = A + (size_t)gr * K + kq;

    // ---- GEMM1: A @ W1^T -> acc ----
    f4 acc[RT][NCT1];
#pragma unroll
    for (int rt = 0; rt < RT; ++rt)
#pragma unroll
        for (int ct = 0; ct < NCT1; ++ct) acc[rt][ct] = (f4){0.f, 0.f, 0.f, 0.f};

    // W frag addressing: Wq1 + (c*(MH/16) + wq*NCT1 + ct)*512 + lane*8
    const unsigned short* w1b = Wq1 + (size_t)(wq * NCT1) * 512 + (size_t)lane * 8;

    h8 wv[NCT1], wvn[NCT1];
#pragma unroll
    for (int ct = 0; ct < NCT1; ++ct)            // Wset(0)
        wv[ct] = *(const h8*)(w1b + ct * 512);
    // prologue stages (vmem order: Wset0 x4, S0, S1, S2)
    gl_lds16(gA + 0 * 32, Ab + (0 & 3) * 2048 + wq * 512);
    gl_lds16(gA + 1 * 32, Ab + (1 & 3) * 2048 + wq * 512);
    gl_lds16(gA + 2 * 32, Ab + (2 & 3) * 2048 + wq * 512);

#pragma unroll
    for (int c = 0; c < NCH1; ++c) {
        // after-counts (vmem issued after stage(c)); exact for the emission
        // order above; compiler sinking only strengthens the wait.
        int nc;
        if (NCH1 == 8) nc = (c == 0) ? 2 : (c == 1) ? 6 : (c == 6) ? 9 : (c == 7) ? 8 : 10;
        else           nc = (c == 0) ? 2 : (c == 1) ? 6 : (c == 2) ? 9 : 8;
        waitvn(nc);
        __builtin_amdgcn_s_barrier();
        if (c + 1 < NCH1) {
#pragma unroll
            for (int ct = 0; ct < NCT1; ++ct)
                wvn[ct] = *(const h8*)(w1b + ((size_t)(c + 1) * (MH / 16) + ct) * 512);
        }
        if (c + 3 < NCH1)
            gl_lds16(gA + (c + 3) * 32, Ab + ((c + 3) & 3) * 2048 + wq * 512);

        const unsigned short* ab = Ab + (c & 3) * 2048;
        h8 ah[RT];
#pragma unroll
        for (int rt = 0; rt < RT; ++rt)
            ah[rt] = *(const h8*)(ab + rt * 512 + lane * 8);
#pragma unroll
        for (int ct = 0; ct < NCT1; ++ct)
#pragma unroll
            for (int rt = 0; rt < RT; ++rt)
                acc[rt][ct] = __builtin_amdgcn_mfma_f32_16x16x32_f16(ah[rt], wv[ct], acc[rt][ct], 0, 0, 0);
        if (c + 1 < NCH1) {
#pragma unroll
            for (int ct = 0; ct < NCT1; ++ct) wv[ct] = wvn[ct];
        }
    }

    // ---- H = relu(acc + b1) -> single fp16 LDS plane ----
#pragma unroll
    for (int ct = 0; ct < NCT1; ++ct) {
        const int col = wq * 64 + ct * 16 + lm;
        const float bv = b1[col];
#pragma unroll
        for (int rt = 0; rt < RT; ++rt) {
#pragma unroll
            for (int reg = 0; reg < 4; ++reg) {
                int rrow = rt * 16 + lq * 4 + reg;
                float v = acc[rt][ct][reg] + bv;
                v = v > 0.f ? v : 0.f;
                Hs[rrow * HS + col] = f2h(v);
            }
        }
    }

    // Wset2(0) before the barrier (latency hides under the drain)
    const unsigned short* w2b = Wq2 + (size_t)(wq * NCT2) * 512 + (size_t)lane * 8;
    h8 wv2[NCT2], wv2n[NCT2];
#pragma unroll
    for (int ct = 0; ct < NCT2; ++ct)
        wv2[ct] = *(const h8*)(w2b + ct * 512);
    __syncthreads();   // full drain: H writes visible to all waves

    // ---- GEMM2: H @ W2^T + b2 -> C ----
    f4 acc2[RT][NCT2];
#pragma unroll
    for (int rt = 0; rt < RT; ++rt)
#pragma unroll
        for (int ct = 0; ct < NCT2; ++ct) acc2[rt][ct] = (f4){0.f, 0.f, 0.f, 0.f};

#pragma unroll
    for (int c = 0; c < NCH2; ++c) {
        if (c + 1 < NCH2) {
#pragma unroll
            for (int ct = 0; ct < NCT2; ++ct)
                wv2n[ct] = *(const h8*)(w2b + ((size_t)(c + 1) * (MO / 16) + ct) * 512);
        }
        const int kk = c * 32 + kq;
        h8 hh[RT];
#pragma unroll
        for (int rt = 0; rt < RT; ++rt)
            hh[rt] = *(const h8*)(Hs + (rt * 16 + lm) * HS + kk);
#pragma unroll
        for (int ct = 0; ct < NCT2; ++ct)
#pragma unroll
            for (int rt = 0; rt < RT; ++rt)
                acc2[rt][ct] = __builtin_amdgcn_mfma_f32_16x16x32_f16(hh[rt], wv2[ct], acc2[rt][ct], 0, 0, 0);
        if (c + 1 < NCH2) {
#pragma unroll
            for (int ct = 0; ct < NCT2; ++ct) wv2[ct] = wv2n[ct];
        }
    }

#pragma unroll
    for (int ct = 0; ct < NCT2; ++ct) {
        const int col = wq * (MO / 4) + ct * 16 + lm;
        const float bv = b2[col];
#pragma unroll
        for (int rt = 0; rt < RT; ++rt) {
#pragma unroll
            for (int reg = 0; reg < 4; ++reg) {
                int n = r0 + rt * 16 + lq * 4 + reg;
                if (n < N) {
                    float v = acc2[rt][ct][reg] + bv;
                    if constexpr (OHALF)
                        ((unsigned short*)Cv)[(size_t)n * MO + col] = f2h(v);
                    else
                        ((float*)Cv)[(size_t)n * MO + col] = v;
                }
            }
        }
    }
}

extern "C" void kernel_launch(void* const* d_in, const int* in_sizes, int n_in,
                              void* d_out, int out_size, void* d_ws, size_t ws_size,
                              hipStream_t stream) {
    const float* x    = (const float*)d_in[0];
    const int*   row  = (const int*)d_in[1];
    const int*   col  = (const int*)d_in[2];
    const float* vals = (const float*)d_in[3];
    const float* eps0 = (const float*)d_in[4];
    const float* W1a  = (const float*)d_in[5];
    const float* b1a  = (const float*)d_in[6];
    const float* W2a  = (const float*)d_in[7];
    const float* b2a  = (const float*)d_in[8];
    const float* eps1 = (const float*)d_in[9];
    const float* W1b  = (const float*)d_in[10];
    const float* b1b  = (const float*)d_in[11];
    const float* W2b  = (const float*)d_in[12];
    const float* b2b  = (const float*)d_in[13];
    const float* Wf1  = (const float*)d_in[14];
    const float* bf1  = (const float*)d_in[15];
    const float* Wf2  = (const float*)d_in[16];
    const float* bf2  = (const float*)d_in[17];
    float* out = (float*)d_out;

    const int N = in_sizes[0] / 128;  // 100000
    const int E = in_sizes[1];        // 1600000

    char* w = (char*)d_ws;
    auto alloc = [&](size_t bytes) -> void* {
        void* p = (void*)w;
        w += (bytes + 255) & ~(size_t)255;
        return p;
    };
    unsigned short* Y      = (unsigned short*)alloc((size_t)N * 256 * 2); // spmm out
    unsigned short* Hb     = (unsigned short*)alloc((size_t)N * 256 * 2); // fp16 activations
    unsigned short* xh     = (unsigned short*)alloc((size_t)N * 128 * 2); // fp16 input copy
    int*            cnt    = (int*)alloc((size_t)N * 4);
    int*            basep  = (int*)alloc((size_t)(N + 1) * 4);
    int*            cursor = (int*)alloc((size_t)N * 4);
    int*            part   = (int*)alloc(1024);
    int2*           edges  = (int2*)alloc((size_t)E * 8);
    unsigned short* Wq1a = (unsigned short*)alloc((size_t)128 * 256 * 2);
    unsigned short* Wq2a = (unsigned short*)alloc((size_t)256 * 256 * 2);
    unsigned short* Wq1b = (unsigned short*)alloc((size_t)256 * 256 * 2);
    unsigned short* Wq2b = (unsigned short*)alloc((size_t)256 * 256 * 2);
    unsigned short* Wqf1 = (unsigned short*)alloc((size_t)256 * 256 * 2);
    unsigned short* Wqf2 = (unsigned short*)alloc((size_t)256 * 64 * 2);

    // ---- CSR build ----
    k_zero<<<(N + 255) / 256, 256, 0, stream>>>(cnt, N);
    k_hist<<<(E + 255) / 256, 256, 0, stream>>>(row, cnt, E);
    int nb = (N + 1023) / 1024;  // 98
    k_scan1<<<nb, 256, 0, stream>>>(cnt, basep, part, N);
    k_scan2<<<1, 256, 0, stream>>>(part, nb);
    k_scan3<<<(N + 255) / 256, 256, 0, stream>>>(basep, cursor, part, N, E);
    k_scatter<<<(E + 255) / 256, 256, 0, stream>>>(row, col, vals, cursor, edges, E);

    // ---- weight fp16 swizzle, input fp16 cast ----
    k_wprep_all<<<1216, 256, 0, stream>>>(W1a, Wq1a, W2a, Wq2a, W1b, Wq1b,
                                          W2b, Wq2b, Wf1, Wqf1, Wf2, Wqf2);
    k_cvt<<<(N * 128 / 4 + 255) / 256, 256, 0, stream>>>(x, xh, N * 128);

    const int mlp_grid  = (N + 63) / 64;
    const int spmm_grid = (N + 3) / 4;

    // ---- conv A ----
    k_spmm_h<128><<<spmm_grid, 256, 0, stream>>>(basep, edges, xh, Y, eps0, N);
    k_mlp<128, 256, true><<<mlp_grid, 256, 0, stream>>>(Y, Wq1a, b1a, Wq2a, b2a, Hb, N);

    // ---- conv B ----
    k_spmm_h<256><<<spmm_grid, 256, 0, stream>>>(basep, edges, Hb, Y, eps1, N);
    k_mlp<256, 256, true><<<mlp_grid, 256, 0, stream>>>(Y, Wq1b, b1b, Wq2b, b2b, Hb, N);

    // ---- head ----
    k_mlp<256, 64, false><<<mlp_grid, 256, 0, stream>>>(Hb, Wqf1, bf1, Wqf2, bf2, out, N);
}

// Round 4
// 643.025 us; speedup vs baseline: 1.1967x; 1.0008x over previous
//
#include <hip/hip_runtime.h>
#include <cstdint>
#include <cstddef>

// ---------------------------------------------------------------------------
// GIN forward: h = conv(x; eps0, W1a,W2a) -> conv(h; eps1, W1b,W2b) -> MLP head
// R14: MLP GEMM1 = whole-A-tile prefetch. The per-block A tile (64 rows x K)
//      is only 16-32 KB: stage ALL of it via global_load_lds in the prologue,
//      one __syncthreads (full drain, once), then the K-phase loop runs with
//      ZERO barriers and ZERO in-loop A waits (pure ds_read + MFMA + 1-deep
//      W register prefetch). A region in LDS aliases the H region (A is dead
//      before H is written; barrier between). 3 barriers total per kernel.
//      R13 post-mortem: ring-3 lead (~450cyc) < HBM latency (~900cyc) and a
//      barrier+wait event every ~150cyc phase kept MLP at ~100us.
// SpMM: unchanged (single fp16 Y plane).
// MLP:  256 thr = 4 waves, 64-row tiles. LDS = max(A 32KB, H 33.8KB) = 33.8KB.
//      launch_bounds(256,3): VGPR cap 170, est ~140 -> no spill, 12 waves/CU.
// ---------------------------------------------------------------------------

using h8  = __attribute__((ext_vector_type(8))) _Float16;       // 8 fp16 = 4 VGPRs
using us8 = __attribute__((ext_vector_type(8))) unsigned short;
using f4  = __attribute__((ext_vector_type(4))) float;          // mfma acc

__device__ inline unsigned short f2h(float f) {   // RNE f32 -> fp16 bits
    _Float16 h = (_Float16)f;
    unsigned short u;
    __builtin_memcpy(&u, &h, 2);
    return u;
}

// async 16B/lane global -> LDS. dst wave-uniform; HW writes lane i at +i*16.
__device__ inline void gl_lds16(const unsigned short* src, unsigned short* dst) {
    __builtin_amdgcn_global_load_lds(
        (const __attribute__((address_space(1))) unsigned int*)src,
        (__attribute__((address_space(3))) unsigned int*)dst, 16, 0, 0);
}

__global__ __launch_bounds__(256) void k_zero(int* p, int n) {
    int i = blockIdx.x * 256 + threadIdx.x;
    if (i < n) p[i] = 0;
}

__global__ __launch_bounds__(256) void k_hist(const int* __restrict__ row,
                                              int* __restrict__ cnt, int E) {
    int e = blockIdx.x * 256 + threadIdx.x;
    if (e < E) atomicAdd(&cnt[row[e]], 1);
}

__global__ __launch_bounds__(256) void k_scan1(const int* __restrict__ cnt,
                                               int* __restrict__ base,
                                               int* __restrict__ part, int N) {
    __shared__ int sd[256];
    int t = threadIdx.x;
    int i0 = blockIdx.x * 1024 + t * 4;
    int v0 = (i0 + 0 < N) ? cnt[i0 + 0] : 0;
    int v1 = (i0 + 1 < N) ? cnt[i0 + 1] : 0;
    int v2 = (i0 + 2 < N) ? cnt[i0 + 2] : 0;
    int v3 = (i0 + 3 < N) ? cnt[i0 + 3] : 0;
    int ts = v0 + v1 + v2 + v3;
    sd[t] = ts;
    __syncthreads();
    for (int off = 1; off < 256; off <<= 1) {
        int x = (t >= off) ? sd[t - off] : 0;
        __syncthreads();
        sd[t] += x;
        __syncthreads();
    }
    int excl = sd[t] - ts;
    if (i0 + 0 < N) base[i0 + 0] = excl;
    if (i0 + 1 < N) base[i0 + 1] = excl + v0;
    if (i0 + 2 < N) base[i0 + 2] = excl + v0 + v1;
    if (i0 + 3 < N) base[i0 + 3] = excl + v0 + v1 + v2;
    if (t == 255) part[blockIdx.x] = sd[255];
}

__global__ __launch_bounds__(256) void k_scan2(int* part, int NB) {
    __shared__ int sd[256];
    int t = threadIdx.x;
    int v = (t < NB) ? part[t] : 0;
    sd[t] = v;
    __syncthreads();
    for (int off = 1; off < 256; off <<= 1) {
        int x = (t >= off) ? sd[t - off] : 0;
        __syncthreads();
        sd[t] += x;
        __syncthreads();
    }
    if (t < NB) part[t] = sd[t] - v;
}

__global__ __launch_bounds__(256) void k_scan3(int* __restrict__ base,
                                               int* __restrict__ cursor,
                                               const int* __restrict__ part,
                                               int N, int E) {
    int i = blockIdx.x * 256 + threadIdx.x;
    if (i < N) {
        int b = base[i] + part[i >> 10];
        base[i] = b;
        cursor[i] = b;
    }
    if (i == 0) base[N] = E;
}

__global__ __launch_bounds__(256) void k_scatter(const int* __restrict__ row,
                                                 const int* __restrict__ col,
                                                 const float* __restrict__ vals,
                                                 int* __restrict__ cursor,
                                                 int2* __restrict__ edges, int E) {
    int e = blockIdx.x * 256 + threadIdx.x;
    if (e < E) {
        int p = atomicAdd(&cursor[row[e]], 1);
        edges[p] = make_int2(col[e], __float_as_int(vals[e]));
    }
}

// fp32 -> fp16 cast, 4 elems/thread (n divisible by 4)
__global__ __launch_bounds__(256) void k_cvt(const float* __restrict__ x,
                                             unsigned short* __restrict__ xh, int n) {
    int i = (blockIdx.x * 256 + threadIdx.x) * 4;
    if (i < n) {
        float4 v = *(const float4*)(x + i);
        ushort4 o = {f2h(v.x), f2h(v.y), f2h(v.z), f2h(v.w)};
        *(ushort4*)(xh + i) = o;
    }
}

// ---------------------------------------------------------------------------
// Wave-per-node CSR SpMM on fp16 rows, fp32 accumulate, fused eps-residual:
//   Y[i] = (1+eps)*Xh[i] + sum_e val[e] * Xh[col[e]]   (single fp16 output)
// ---------------------------------------------------------------------------
template <int D>
__global__ __launch_bounds__(256) void k_spmm_h(const int* __restrict__ base,
                                                const int2* __restrict__ edges,
                                                const unsigned short* __restrict__ Xh,
                                                unsigned short* __restrict__ Y,
                                                const float* __restrict__ epsp,
                                                int N) {
    constexpr int L = D / 8;    // lanes per row (16 or 32)
    constexpr int R = 64 / L;   // edges per gather instr (4 or 2)
    constexpr int U = 8 / R;    // instrs per inner iter -> 8 edges/iter
    int node = blockIdx.x * 4 + (threadIdx.x >> 6);
    if (node >= N) return;
    const int lane = threadIdx.x & 63;
    const int sub  = lane % L;   // 8-col group within row
    const int part = lane / L;   // which edge of the group
    const float scale = 1.0f + epsp[0];

    float acc[8];
#pragma unroll
    for (int k = 0; k < 8; ++k) acc[k] = 0.0f;

    const int s = base[node];
    const int e = base[node + 1];
    for (int i0 = s; i0 < e; i0 += 64) {
        int rem = e - i0;
        int idx = i0 + (lane < rem ? lane : 0);
        int2 ed = edges[idx];
        int   ci = ed.x;
        float vi = (lane < rem) ? __int_as_float(ed.y) : 0.0f;
        int lim = rem < 64 ? rem : 64;
        for (int j = 0; j < lim; j += 8) {
            int cc[U]; float vv[U];
#pragma unroll
            for (int u = 0; u < U; ++u) {
                int sl = j + u * R + part;      // <= 63 always
                cc[u] = __shfl(ci, sl);
                vv[u] = __shfl(vi, sl);
            }
            h8 g[U];
#pragma unroll
            for (int u = 0; u < U; ++u)
                g[u] = *(const h8*)(Xh + (size_t)cc[u] * D + sub * 8);
#pragma unroll
            for (int u = 0; u < U; ++u)
#pragma unroll
                for (int k = 0; k < 8; ++k)
                    acc[k] = fmaf((float)g[u][k], vv[u], acc[k]);
        }
    }

    // butterfly-reduce across edge parts (lanes L, 2L, ... apart)
#pragma unroll
    for (int st = L; st < 64; st <<= 1)
#pragma unroll
        for (int k = 0; k < 8; ++k)
            acc[k] += __shfl_xor(acc[k], st);

    if (part == 0) {
        h8 xs = *(const h8*)(Xh + (size_t)node * D + sub * 8);
        us8 hi8;
#pragma unroll
        for (int k = 0; k < 8; ++k)
            hi8[k] = f2h(acc[k] + scale * (float)xs[k]);
        *(us8*)(Y + (size_t)node * D + sub * 8) = hi8;
    }
}

// ---------------------------------------------------------------------------
// W prep: W[M][K] fp32 -> single fp16 plane in exact B-fragment order for
// mfma_f32_16x16x32_f16:
//   Wf[((c*(M/16)+ct)*64 + lane)*8 + j]
// where B[k][n]: n = ct*16 + (lane&15), k = c*32 + (lane>>4)*8 + j.
// ---------------------------------------------------------------------------
__device__ inline void wprep_body(const float* __restrict__ W,
                                  unsigned short* __restrict__ Wf,
                                  int K, int M, int idx) {
    int group = idx >> 9;          // (c, ct); 512 work-items per group
    int r     = idx & 511;
    int lane  = r >> 3;
    int j     = r & 7;
    int c  = group / (M / 16);
    int ct = group - c * (M / 16);
    int n = ct * 16 + (lane & 15);
    int k = c * 32 + (lane >> 4) * 8 + j;
    float w = W[(size_t)n * K + k];
    Wf[(size_t)group * 512 + (size_t)lane * 8 + j] = f2h(w);
}

__global__ __launch_bounds__(256) void k_wprep_all(
        const float* W1a, unsigned short* Q1a, const float* W2a, unsigned short* Q2a,
        const float* W1b, unsigned short* Q1b, const float* W2b, unsigned short* Q2b,
        const float* Wf1, unsigned short* Qf1, const float* Wf2, unsigned short* Qf2) {
    int b = blockIdx.x;
    const float* W; unsigned short* Q; int K, M, lb;
    if      (b < 128)  { W = W1a; Q = Q1a; K = 128; M = 256; lb = b; }
    else if (b < 384)  { W = W2a; Q = Q2a; K = 256; M = 256; lb = b - 128; }
    else if (b < 640)  { W = W1b; Q = Q1b; K = 256; M = 256; lb = b - 384; }
    else if (b < 896)  { W = W2b; Q = Q2b; K = 256; M = 256; lb = b - 640; }
    else if (b < 1152) { W = Wf1; Q = Qf1; K = 256; M = 256; lb = b - 896; }
    else               { W = Wf2; Q = Qf2; K = 256; M = 64;  lb = b - 1152; }
    wprep_body(W, Q, K, M, lb * 256 + threadIdx.x);
}

// ---------------------------------------------------------------------------
// Fused MLP: C = relu(A @ W1^T + b1) @ W2^T + b2    (A: [N,K] fp16, hidden
// 256, out MO). Block = 256 thr = 4 waves; tile = 64 rows (RT=4 per wave,
// each wave owns a 64-col slice in GEMM1).
//
// GEMM1 (whole-A prefetch):
//   prologue: load Wset(0) to regs; stage ALL NCH1 32-k chunks of the 64-row
//             A tile into LDS (wave w stages rows r0+16w..+15, fragment
//             order -> stage dest wave-uniform, read = lane-linear b128,
//             conflict-free); __syncthreads (full drain, once).
//   phases (NO barriers, NO A waits): load Wset(c+1) -> ds_read A frags(c)
//             -> 16 MFMA.  W is L2-resident, 1 phase (~150cy) of lead.
//   A LDS region ALIASES the H region: A dead after last phase's ds_reads;
//   barrier; H-write; barrier; GEMM2 (H from LDS, W2 1-deep; no barriers).
// LDS = max(A: NCH1*4KB <= 32KB, H: 64*264*2 = 33.8KB) = 33.8KB.
// ---------------------------------------------------------------------------
template <int K, int MO, bool OHALF>
__global__ __launch_bounds__(256, 3) void k_mlp(const unsigned short* __restrict__ A,
                                                const unsigned short* __restrict__ Wq1,
                                                const float* __restrict__ b1,
                                                const unsigned short* __restrict__ Wq2,
                                                const float* __restrict__ b2,
                                                void* __restrict__ Cv, int N) {
    constexpr int MH   = 256;
    constexpr int RT   = 4;         // 4 row-tiles of 16 -> 64 rows/block
    constexpr int NCT1 = MH / 64;   // 4 col-tiles per wave (GEMM1)
    constexpr int NCH1 = K / 32;    // 4 or 8
    constexpr int NCH2 = MH / 32;   // 8
    constexpr int NCT2 = MO / 64 > 0 ? MO / 64 : 1;  // 4 or 1
    constexpr int HS   = 264;       // LDS row stride in halves
    // union: A tile (NCH1*2048 halves <= 16384) | H plane (64*HS = 16896)
    __shared__ unsigned short S[64 * HS];

    const int t    = threadIdx.x;
    const int lane = t & 63;
    const int wq   = t >> 6;
    const int r0   = blockIdx.x * 64;
    const int lm   = lane & 15;
    const int lq   = lane >> 4;
    const int kq   = lq * 8;        // k-offset within chunk for this quad

    // global A source for staging: wave w stages rows r0+w*16+lm, k = c*32+kq
    int gr = r0 + wq * 16 + lm;
    if (gr >= N) gr = N - 1;        // clamp: valid mem; clamped rows unused
    const unsigned short* gA = A + (size_t)gr * K + kq;

    // ---- GEMM1 prologue: Wset(0) + whole A tile -> LDS, one drain ----
    const unsigned short* w1b = Wq1 + (size_t)(wq * NCT1) * 512 + (size_t)lane * 8;
    h8 wv[NCT1], wvn[NCT1];
#pragma unroll
    for (int ct = 0; ct < NCT1; ++ct)
        wv[ct] = *(const h8*)(w1b + ct * 512);
#pragma unroll
    for (int c = 0; c < NCH1; ++c)
        gl_lds16(gA + c * 32, S + c * 2048 + wq * 512);
    __syncthreads();   // all stages (all waves) landed; zero waits hereafter

    f4 acc[RT][NCT1];
#pragma unroll
    for (int rt = 0; rt < RT; ++rt)
#pragma unroll
        for (int ct = 0; ct < NCT1; ++ct) acc[rt][ct] = (f4){0.f, 0.f, 0.f, 0.f};

    // ---- GEMM1 phases: no barriers, no vmem waits on A ----
#pragma unroll
    for (int c = 0; c < NCH1; ++c) {
        if (c + 1 < NCH1) {
#pragma unroll
            for (int ct = 0; ct < NCT1; ++ct)
                wvn[ct] = *(const h8*)(w1b + ((size_t)(c + 1) * (MH / 16) + ct) * 512);
        }
        const unsigned short* ab = S + c * 2048;
        h8 ah[RT];
#pragma unroll
        for (int rt = 0; rt < RT; ++rt)
            ah[rt] = *(const h8*)(ab + rt * 512 + lane * 8);
#pragma unroll
        for (int ct = 0; ct < NCT1; ++ct)
#pragma unroll
            for (int rt = 0; rt < RT; ++rt)
                acc[rt][ct] = __builtin_amdgcn_mfma_f32_16x16x32_f16(ah[rt], wv[ct], acc[rt][ct], 0, 0, 0);
        if (c + 1 < NCH1) {
#pragma unroll
            for (int ct = 0; ct < NCT1; ++ct) wv[ct] = wvn[ct];
        }
    }
    __syncthreads();   // all waves done reading A region; safe to write H

    // ---- H = relu(acc + b1) -> fp16 LDS plane (aliases A region) ----
#pragma unroll
    for (int ct = 0; ct < NCT1; ++ct) {
        const int col = wq * 64 + ct * 16 + lm;
        const float bv = b1[col];
#pragma unroll
        for (int rt = 0; rt < RT; ++rt) {
#pragma unroll
            for (int reg = 0; reg < 4; ++reg) {
                int rrow = rt * 16 + lq * 4 + reg;
                float v = acc[rt][ct][reg] + bv;
                v = v > 0.f ? v : 0.f;
                S[rrow * HS + col] = f2h(v);
            }
        }
    }

    // Wset2(0) before the barrier (latency hides under the drain)
    const unsigned short* w2b = Wq2 + (size_t)(wq * NCT2) * 512 + (size_t)lane * 8;
    h8 wv2[NCT2], wv2n[NCT2];
#pragma unroll
    for (int ct = 0; ct < NCT2; ++ct)
        wv2[ct] = *(const h8*)(w2b + ct * 512);
    __syncthreads();   // H visible to all waves

    // ---- GEMM2: H @ W2^T + b2 -> C (no barriers) ----
    f4 acc2[RT][NCT2];
#pragma unroll
    for (int rt = 0; rt < RT; ++rt)
#pragma unroll
        for (int ct = 0; ct < NCT2; ++ct) acc2[rt][ct] = (f4){0.f, 0.f, 0.f, 0.f};

#pragma unroll
    for (int c = 0; c < NCH2; ++c) {
        if (c + 1 < NCH2) {
#pragma unroll
            for (int ct = 0; ct < NCT2; ++ct)
                wv2n[ct] = *(const h8*)(w2b + ((size_t)(c + 1) * (MO / 16) + ct) * 512);
        }
        const int kk = c * 32 + kq;
        h8 hh[RT];
#pragma unroll
        for (int rt = 0; rt < RT; ++rt)
            hh[rt] = *(const h8*)(S + (rt * 16 + lm) * HS + kk);
#pragma unroll
        for (int ct = 0; ct < NCT2; ++ct)
#pragma unroll
            for (int rt = 0; rt < RT; ++rt)
                acc2[rt][ct] = __builtin_amdgcn_mfma_f32_16x16x32_f16(hh[rt], wv2[ct], acc2[rt][ct], 0, 0, 0);
        if (c + 1 < NCH2) {
#pragma unroll
            for (int ct = 0; ct < NCT2; ++ct) wv2[ct] = wv2n[ct];
        }
    }

#pragma unroll
    for (int ct = 0; ct < NCT2; ++ct) {
        const int col = wq * (MO / 4) + ct * 16 + lm;
        const float bv = b2[col];
#pragma unroll
        for (int rt = 0; rt < RT; ++rt) {
#pragma unroll
            for (int reg = 0; reg < 4; ++reg) {
                int n = r0 + rt * 16 + lq * 4 + reg;
                if (n < N) {
                    float v = acc2[rt][ct][reg] + bv;
                    if constexpr (OHALF)
                        ((unsigned short*)Cv)[(size_t)n * MO + col] = f2h(v);
                    else
                        ((float*)Cv)[(size_t)n * MO + col] = v;
                }
            }
        }
    }
}

extern "C" void kernel_launch(void* const* d_in, const int* in_sizes, int n_in,
                              void* d_out, int out_size, void* d_ws, size_t ws_size,
                              hipStream_t stream) {
    const float* x    = (const float*)d_in[0];
    const int*   row  = (const int*)d_in[1];
    const int*   col  = (const int*)d_in[2];
    const float* vals = (const float*)d_in[3];
    const float* eps0 = (const float*)d_in[4];
    const float* W1a  = (const float*)d_in[5];
    const float* b1a  = (const float*)d_in[6];
    const float* W2a  = (const float*)d_in[7];
    const float* b2a  = (const float*)d_in[8];
    const float* eps1 = (const float*)d_in[9];
    const float* W1b  = (const float*)d_in[10];
    const float* b1b  = (const float*)d_in[11];
    const float* W2b  = (const float*)d_in[12];
    const float* b2b  = (const float*)d_in[13];
    const float* Wf1  = (const float*)d_in[14];
    const float* bf1  = (const float*)d_in[15];
    const float* Wf2  = (const float*)d_in[16];
    const float* bf2  = (const float*)d_in[17];
    float* out = (float*)d_out;

    const int N = in_sizes[0] / 128;  // 100000
    const int E = in_sizes[1];        // 1600000

    char* w = (char*)d_ws;
    auto alloc = [&](size_t bytes) -> void* {
        void* p = (void*)w;
        w += (bytes + 255) & ~(size_t)255;
        return p;
    };
    unsigned short* Y      = (unsigned short*)alloc((size_t)N * 256 * 2); // spmm out
    unsigned short* Hb     = (unsigned short*)alloc((size_t)N * 256 * 2); // fp16 activations
    unsigned short* xh     = (unsigned short*)alloc((size_t)N * 128 * 2); // fp16 input copy
    int*            cnt    = (int*)alloc((size_t)N * 4);
    int*            basep  = (int*)alloc((size_t)(N + 1) * 4);
    int*            cursor = (int*)alloc((size_t)N * 4);
    int*            part   = (int*)alloc(1024);
    int2*           edges  = (int2*)alloc((size_t)E * 8);
    unsigned short* Wq1a = (unsigned short*)alloc((size_t)128 * 256 * 2);
    unsigned short* Wq2a = (unsigned short*)alloc((size_t)256 * 256 * 2);
    unsigned short* Wq1b = (unsigned short*)alloc((size_t)256 * 256 * 2);
    unsigned short* Wq2b = (unsigned short*)alloc((size_t)256 * 256 * 2);
    unsigned short* Wqf1 = (unsigned short*)alloc((size_t)256 * 256 * 2);
    unsigned short* Wqf2 = (unsigned short*)alloc((size_t)256 * 64 * 2);

    // ---- CSR build ----
    k_zero<<<(N + 255) / 256, 256, 0, stream>>>(cnt, N);
    k_hist<<<(E + 255) / 256, 256, 0, stream>>>(row, cnt, E);
    int nb = (N + 1023) / 1024;  // 98
    k_scan1<<<nb, 256, 0, stream>>>(cnt, basep, part, N);
    k_scan2<<<1, 256, 0, stream>>>(part, nb);
    k_scan3<<<(N + 255) / 256, 256, 0, stream>>>(basep, cursor, part, N, E);
    k_scatter<<<(E + 255) / 256, 256, 0, stream>>>(row, col, vals, cursor, edges, E);

    // ---- weight fp16 swizzle, input fp16 cast ----
    k_wprep_all<<<1216, 256, 0, stream>>>(W1a, Wq1a, W2a, Wq2a, W1b, Wq1b,
                                          W2b, Wq2b, Wf1, Wqf1, Wf2, Wqf2);
    k_cvt<<<(N * 128 / 4 + 255) / 256, 256, 0, stream>>>(x, xh, N * 128);

    const int mlp_grid  = (N + 63) / 64;
    const int spmm_grid = (N + 3) / 4;

    // ---- conv A ----
    k_spmm_h<128><<<spmm_grid, 256, 0, stream>>>(basep, edges, xh, Y, eps0, N);
    k_mlp<128, 256, true><<<mlp_grid, 256, 0, stream>>>(Y, Wq1a, b1a, Wq2a, b2a, Hb, N);

    // ---- conv B ----
    k_spmm_h<256><<<spmm_grid, 256, 0, stream>>>(basep, edges, Hb, Y, eps1, N);
    k_mlp<256, 256, true><<<mlp_grid, 256, 0, stream>>>(Y, Wq1b, b1b, Wq2b, b2b, Hb, N);

    // ---- head ----
    k_mlp<256, 64, false><<<mlp_grid, 256, 0, stream>>>(Hb, Wqf1, bf1, Wqf2, bf2, out, N);
}

// Round 5
// 602.804 us; speedup vs baseline: 1.2766x; 1.0667x over previous
//
#include <hip/hip_runtime.h>
#include <cstdint>
#include <cstddef>

// ---------------------------------------------------------------------------
// GIN forward: h = conv(x; eps0, W1a,W2a) -> conv(h; eps1, W1b,W2b) -> MLP head
// R15: FUSED conv kernel k_conv = SpMM gather + GEMM1 + GEMM2 per 64-row
//      block. Eliminates the Y round-trip (77 MB write + 77 MB fetch) on the
//      measured ~3.75 TB/s scatter-fetch path, and 2 dispatches.
//      R14 post-mortem: two different GEMM1 schedules gave IDENTICAL totals;
//      spmm time tracks hbm_bytes/3.75 TB/s across rounds -> the workload is
//      bytes-bound on the fetch path; remove bytes, not stalls.
//      Gather results are ds_write'd straight into the A-fragment LDS buffer
//      (fragment order, slot ^= (sub&7) XOR swizzle; read key (4c+q)&7).
//      Quantization path fp32->f2h->MFMA is bit-identical to R14 => absmax
//      must stay exactly 0.00390625 (correctness tripwire).
// ---------------------------------------------------------------------------

using h8  = __attribute__((ext_vector_type(8))) _Float16;       // 8 fp16 = 4 VGPRs
using us8 = __attribute__((ext_vector_type(8))) unsigned short;
using f4  = __attribute__((ext_vector_type(4))) float;          // mfma acc

__device__ inline unsigned short f2h(float f) {   // RNE f32 -> fp16 bits
    _Float16 h = (_Float16)f;
    unsigned short u;
    __builtin_memcpy(&u, &h, 2);
    return u;
}

// async 16B/lane global -> LDS. dst wave-uniform; HW writes lane i at +i*16.
__device__ inline void gl_lds16(const unsigned short* src, unsigned short* dst) {
    __builtin_amdgcn_global_load_lds(
        (const __attribute__((address_space(1))) unsigned int*)src,
        (__attribute__((address_space(3))) unsigned int*)dst, 16, 0, 0);
}

__global__ __launch_bounds__(256) void k_zero(int* p, int n) {
    int i = blockIdx.x * 256 + threadIdx.x;
    if (i < n) p[i] = 0;
}

__global__ __launch_bounds__(256) void k_hist(const int* __restrict__ row,
                                              int* __restrict__ cnt, int E) {
    int e = blockIdx.x * 256 + threadIdx.x;
    if (e < E) atomicAdd(&cnt[row[e]], 1);
}

__global__ __launch_bounds__(256) void k_scan1(const int* __restrict__ cnt,
                                               int* __restrict__ base,
                                               int* __restrict__ part, int N) {
    __shared__ int sd[256];
    int t = threadIdx.x;
    int i0 = blockIdx.x * 1024 + t * 4;
    int v0 = (i0 + 0 < N) ? cnt[i0 + 0] : 0;
    int v1 = (i0 + 1 < N) ? cnt[i0 + 1] : 0;
    int v2 = (i0 + 2 < N) ? cnt[i0 + 2] : 0;
    int v3 = (i0 + 3 < N) ? cnt[i0 + 3] : 0;
    int ts = v0 + v1 + v2 + v3;
    sd[t] = ts;
    __syncthreads();
    for (int off = 1; off < 256; off <<= 1) {
        int x = (t >= off) ? sd[t - off] : 0;
        __syncthreads();
        sd[t] += x;
        __syncthreads();
    }
    int excl = sd[t] - ts;
    if (i0 + 0 < N) base[i0 + 0] = excl;
    if (i0 + 1 < N) base[i0 + 1] = excl + v0;
    if (i0 + 2 < N) base[i0 + 2] = excl + v0 + v1;
    if (i0 + 3 < N) base[i0 + 3] = excl + v0 + v1 + v2;
    if (t == 255) part[blockIdx.x] = sd[255];
}

__global__ __launch_bounds__(256) void k_scan2(int* part, int NB) {
    __shared__ int sd[256];
    int t = threadIdx.x;
    int v = (t < NB) ? part[t] : 0;
    sd[t] = v;
    __syncthreads();
    for (int off = 1; off < 256; off <<= 1) {
        int x = (t >= off) ? sd[t - off] : 0;
        __syncthreads();
        sd[t] += x;
        __syncthreads();
    }
    if (t < NB) part[t] = sd[t] - v;
}

__global__ __launch_bounds__(256) void k_scan3(int* __restrict__ base,
                                               int* __restrict__ cursor,
                                               const int* __restrict__ part,
                                               int N, int E) {
    int i = blockIdx.x * 256 + threadIdx.x;
    if (i < N) {
        int b = base[i] + part[i >> 10];
        base[i] = b;
        cursor[i] = b;
    }
    if (i == 0) base[N] = E;
}

__global__ __launch_bounds__(256) void k_scatter(const int* __restrict__ row,
                                                 const int* __restrict__ col,
                                                 const float* __restrict__ vals,
                                                 int* __restrict__ cursor,
                                                 int2* __restrict__ edges, int E) {
    int e = blockIdx.x * 256 + threadIdx.x;
    if (e < E) {
        int p = atomicAdd(&cursor[row[e]], 1);
        edges[p] = make_int2(col[e], __float_as_int(vals[e]));
    }
}

// fp32 -> fp16 cast, 4 elems/thread (n divisible by 4)
__global__ __launch_bounds__(256) void k_cvt(const float* __restrict__ x,
                                             unsigned short* __restrict__ xh, int n) {
    int i = (blockIdx.x * 256 + threadIdx.x) * 4;
    if (i < n) {
        float4 v = *(const float4*)(x + i);
        ushort4 o = {f2h(v.x), f2h(v.y), f2h(v.z), f2h(v.w)};
        *(ushort4*)(xh + i) = o;
    }
}

// ---------------------------------------------------------------------------
// W prep: W[M][K] fp32 -> single fp16 plane in exact B-fragment order for
// mfma_f32_16x16x32_f16:
//   Wf[((c*(M/16)+ct)*64 + lane)*8 + j]
// where B[k][n]: n = ct*16 + (lane&15), k = c*32 + (lane>>4)*8 + j.
// ---------------------------------------------------------------------------
__device__ inline void wprep_body(const float* __restrict__ W,
                                  unsigned short* __restrict__ Wf,
                                  int K, int M, int idx) {
    int group = idx >> 9;          // (c, ct); 512 work-items per group
    int r     = idx & 511;
    int lane  = r >> 3;
    int j     = r & 7;
    int c  = group / (M / 16);
    int ct = group - c * (M / 16);
    int n = ct * 16 + (lane & 15);
    int k = c * 32 + (lane >> 4) * 8 + j;
    float w = W[(size_t)n * K + k];
    Wf[(size_t)group * 512 + (size_t)lane * 8 + j] = f2h(w);
}

__global__ __launch_bounds__(256) void k_wprep_all(
        const float* W1a, unsigned short* Q1a, const float* W2a, unsigned short* Q2a,
        const float* W1b, unsigned short* Q1b, const float* W2b, unsigned short* Q2b,
        const float* Wf1, unsigned short* Qf1, const float* Wf2, unsigned short* Qf2) {
    int b = blockIdx.x;
    const float* W; unsigned short* Q; int K, M, lb;
    if      (b < 128)  { W = W1a; Q = Q1a; K = 128; M = 256; lb = b; }
    else if (b < 384)  { W = W2a; Q = Q2a; K = 256; M = 256; lb = b - 128; }
    else if (b < 640)  { W = W1b; Q = Q1b; K = 256; M = 256; lb = b - 384; }
    else if (b < 896)  { W = W2b; Q = Q2b; K = 256; M = 256; lb = b - 640; }
    else if (b < 1152) { W = Wf1; Q = Qf1; K = 256; M = 256; lb = b - 896; }
    else               { W = Wf2; Q = Qf2; K = 256; M = 64;  lb = b - 1152; }
    wprep_body(W, Q, K, M, lb * 256 + threadIdx.x);
}

// ---------------------------------------------------------------------------
// FUSED GIN conv: out = relu((spmm(A,X) + (1+eps)X) @ W1^T + b1) @ W2^T + b2
// X: [N][DIN] fp16. out: [N][256] fp16. Block = 256 thr = 4 waves, 64 rows.
//
// Phase 1 (spmm): wave w computes rows r0+16w..+15 sequentially. Per node:
//   full-wave multi-edge gather (identical math to the old k_spmm_h),
//   butterfly reduce, + (1+eps)X self term, f2h, then ds_write_b128 into the
//   A-fragment buffer: S[c*2048 + w*512 + q*128 + (j ^ (sub&7))*8], where
//   sub = col/8 = 4c+q, j = row-in-tile. XOR swizzle avoids the 32-way
//   same-bank-quad write conflict of unswizzled fragment order.
// Phase 2 (GEMM1): lane i reads A-frag at S[c*2048 + rt*512 + lq*128 +
//   ((lm ^ ((4c+lq)&7)))*8] (matching key), W1 register-prefetched 1 phase
//   ahead, Wset(0) loaded BEFORE phase 1 (fully hidden). 16 MFMA/phase/wave.
// Phase 3: H=relu(+b1) -> LDS plane (aliases A region); GEMM2 as before.
// LDS = max(A-frag: DIN/32*2048 <= 16K halves, H: 64*264) = 33.8 KB.
// ---------------------------------------------------------------------------
template <int DIN>
__global__ __launch_bounds__(256, 3) void k_conv(const int* __restrict__ base,
                                                 const int2* __restrict__ edges,
                                                 const unsigned short* __restrict__ Xh,
                                                 const unsigned short* __restrict__ Wq1,
                                                 const float* __restrict__ b1,
                                                 const unsigned short* __restrict__ Wq2,
                                                 const float* __restrict__ b2,
                                                 unsigned short* __restrict__ Cout,
                                                 const float* __restrict__ epsp,
                                                 int N) {
    constexpr int MH   = 256;
    constexpr int RT   = 4;          // 4 row-tiles of 16 -> 64 rows/block
    constexpr int NCT1 = MH / 64;    // 4 col-tiles per wave (GEMM1)
    constexpr int NCH1 = DIN / 32;   // 4 or 8
    constexpr int NCH2 = MH / 32;    // 8
    constexpr int NCT2 = MH / 64;    // 4 (out = 256 fp16)
    constexpr int HS   = 264;
    // union: A-frag buffer (NCH1*2048 halves <= 16384) | H plane (64*HS)
    __shared__ unsigned short S[64 * HS];

    const int t    = threadIdx.x;
    const int lane = t & 63;
    const int wq   = t >> 6;
    const int r0   = blockIdx.x * 64;
    const int lm   = lane & 15;
    const int lq   = lane >> 4;
    const int kq   = lq * 8;

    // ---- W1 set(0) prefetch (issued before phase 1: fully hidden) ----
    const unsigned short* w1b = Wq1 + (size_t)(wq * NCT1) * 512 + (size_t)lane * 8;
    h8 wv[NCT1], wvn[NCT1];
#pragma unroll
    for (int ct = 0; ct < NCT1; ++ct)
        wv[ct] = *(const h8*)(w1b + ct * 512);

    // ---- Phase 1: spmm for this wave's 16 rows -> fragment LDS ----
    {
        constexpr int L = DIN / 8;   // lanes per row (16 or 32)
        constexpr int R = 64 / L;    // edges per gather instr (4 or 2)
        constexpr int U = 8 / R;     // instrs per inner iter -> 8 edges/iter
        const int sub  = lane % L;
        const int part = lane / L;
        const float scale = 1.0f + epsp[0];

        // preload segment bounds for all 16 nodes (lane&15 picks the node)
        int nb = r0 + wq * 16 + lm;
        int sv = 0, ev = 0;
        if (nb < N) { sv = base[nb]; ev = base[nb + 1]; }

        for (int j = 0; j < 16; ++j) {
            int n = r0 + wq * 16 + j;
            float acc[8];
#pragma unroll
            for (int k = 0; k < 8; ++k) acc[k] = 0.0f;
            bool valid = (n < N);     // wave-uniform
            if (valid) {
                int s = __shfl(sv, j);
                int e = __shfl(ev, j);
                for (int i0 = s; i0 < e; i0 += 64) {
                    int rem = e - i0;
                    int idx = i0 + (lane < rem ? lane : 0);
                    int2 ed = edges[idx];
                    int   ci = ed.x;
                    float vi = (lane < rem) ? __int_as_float(ed.y) : 0.0f;
                    int lim = rem < 64 ? rem : 64;
                    for (int jj = 0; jj < lim; jj += 8) {
                        int cc[U]; float vv[U];
#pragma unroll
                        for (int u = 0; u < U; ++u) {
                            int sl = jj + u * R + part;   // <= 63 always
                            cc[u] = __shfl(ci, sl);
                            vv[u] = __shfl(vi, sl);
                        }
                        h8 g[U];
#pragma unroll
                        for (int u = 0; u < U; ++u)
                            g[u] = *(const h8*)(Xh + (size_t)cc[u] * DIN + sub * 8);
#pragma unroll
                        for (int u = 0; u < U; ++u)
#pragma unroll
                            for (int k = 0; k < 8; ++k)
                                acc[k] = fmaf((float)g[u][k], vv[u], acc[k]);
                    }
                }
                // butterfly reduce across edge parts
#pragma unroll
                for (int st = L; st < 64; st <<= 1)
#pragma unroll
                    for (int k = 0; k < 8; ++k)
                        acc[k] += __shfl_xor(acc[k], st);
            }
            if (part == 0) {
                us8 o;
                if (valid) {
                    h8 xs = *(const h8*)(Xh + (size_t)n * DIN + sub * 8);
#pragma unroll
                    for (int k = 0; k < 8; ++k)
                        o[k] = f2h(acc[k] + scale * (float)xs[k]);
                } else {
#pragma unroll
                    for (int k = 0; k < 8; ++k) o[k] = 0;
                }
                int c = sub >> 2, q = sub & 3;
                unsigned off = (unsigned)(c * 2048 + wq * 512 + q * 128
                                          + ((j ^ (sub & 7)) * 8));
                *(us8*)(S + off) = o;       // ds_write_b128, <=4-way conflict
            }
        }
    }
    __syncthreads();   // all waves' fragment writes visible

    // ---- GEMM1: A @ W1^T -> acc (A from LDS, W 1-phase prefetch) ----
    f4 acc[RT][NCT1];
#pragma unroll
    for (int rt = 0; rt < RT; ++rt)
#pragma unroll
        for (int ct = 0; ct < NCT1; ++ct) acc[rt][ct] = (f4){0.f, 0.f, 0.f, 0.f};

#pragma unroll
    for (int c = 0; c < NCH1; ++c) {
        if (c + 1 < NCH1) {
#pragma unroll
            for (int ct = 0; ct < NCT1; ++ct)
                wvn[ct] = *(const h8*)(w1b + ((size_t)(c + 1) * (MH / 16) + ct) * 512);
        }
        const int key = (4 * c + lq) & 7;
        h8 ah[RT];
#pragma unroll
        for (int rt = 0; rt < RT; ++rt)
            ah[rt] = *(const h8*)(S + c * 2048 + rt * 512 + lq * 128 + (lm ^ key) * 8);
#pragma unroll
        for (int ct = 0; ct < NCT1; ++ct)
#pragma unroll
            for (int rt = 0; rt < RT; ++rt)
                acc[rt][ct] = __builtin_amdgcn_mfma_f32_16x16x32_f16(ah[rt], wv[ct], acc[rt][ct], 0, 0, 0);
        if (c + 1 < NCH1) {
#pragma unroll
            for (int ct = 0; ct < NCT1; ++ct) wv[ct] = wvn[ct];
        }
    }
    __syncthreads();   // all waves done reading A region; safe to write H

    // ---- H = relu(acc + b1) -> fp16 LDS plane (aliases A region) ----
#pragma unroll
    for (int ct = 0; ct < NCT1; ++ct) {
        const int col = wq * 64 + ct * 16 + lm;
        const float bv = b1[col];
#pragma unroll
        for (int rt = 0; rt < RT; ++rt) {
#pragma unroll
            for (int reg = 0; reg < 4; ++reg) {
                int rrow = rt * 16 + lq * 4 + reg;
                float v = acc[rt][ct][reg] + bv;
                v = v > 0.f ? v : 0.f;
                S[rrow * HS + col] = f2h(v);
            }
        }
    }

    // Wset2(0) before the barrier (latency hides under the drain)
    const unsigned short* w2b = Wq2 + (size_t)(wq * NCT2) * 512 + (size_t)lane * 8;
    h8 wv2[NCT2], wv2n[NCT2];
#pragma unroll
    for (int ct = 0; ct < NCT2; ++ct)
        wv2[ct] = *(const h8*)(w2b + ct * 512);
    __syncthreads();   // H visible to all waves

    // ---- GEMM2: H @ W2^T + b2 -> Cout fp16 ----
    f4 acc2[RT][NCT2];
#pragma unroll
    for (int rt = 0; rt < RT; ++rt)
#pragma unroll
        for (int ct = 0; ct < NCT2; ++ct) acc2[rt][ct] = (f4){0.f, 0.f, 0.f, 0.f};

#pragma unroll
    for (int c = 0; c < NCH2; ++c) {
        if (c + 1 < NCH2) {
#pragma unroll
            for (int ct = 0; ct < NCT2; ++ct)
                wv2n[ct] = *(const h8*)(w2b + ((size_t)(c + 1) * (MH / 16) + ct) * 512);
        }
        const int kk = c * 32 + kq;
        h8 hh[RT];
#pragma unroll
        for (int rt = 0; rt < RT; ++rt)
            hh[rt] = *(const h8*)(S + (rt * 16 + lm) * HS + kk);
#pragma unroll
        for (int ct = 0; ct < NCT2; ++ct)
#pragma unroll
            for (int rt = 0; rt < RT; ++rt)
                acc2[rt][ct] = __builtin_amdgcn_mfma_f32_16x16x32_f16(hh[rt], wv2[ct], acc2[rt][ct], 0, 0, 0);
        if (c + 1 < NCH2) {
#pragma unroll
            for (int ct = 0; ct < NCT2; ++ct) wv2[ct] = wv2n[ct];
        }
    }

#pragma unroll
    for (int ct = 0; ct < NCT2; ++ct) {
        const int col = wq * 64 + ct * 16 + lm;
        const float bv = b2[col];
#pragma unroll
        for (int rt = 0; rt < RT; ++rt) {
#pragma unroll
            for (int reg = 0; reg < 4; ++reg) {
                int n = r0 + rt * 16 + lq * 4 + reg;
                if (n < N)
                    Cout[(size_t)n * MH + col] = f2h(acc2[rt][ct][reg] + bv);
            }
        }
    }
}

// ---------------------------------------------------------------------------
// Head MLP (unchanged R14): C = relu(A @ W1^T + b1) @ W2^T + b2, A fp16
// global (whole-A LDS prefetch), out fp32.
// ---------------------------------------------------------------------------
template <int K, int MO>
__global__ __launch_bounds__(256, 3) void k_mlp(const unsigned short* __restrict__ A,
                                                const unsigned short* __restrict__ Wq1,
                                                const float* __restrict__ b1,
                                                const unsigned short* __restrict__ Wq2,
                                                const float* __restrict__ b2,
                                                float* __restrict__ Cv, int N) {
    constexpr int MH   = 256;
    constexpr int RT   = 4;
    constexpr int NCT1 = MH / 64;
    constexpr int NCH1 = K / 32;
    constexpr int NCH2 = MH / 32;
    constexpr int NCT2 = MO / 64 > 0 ? MO / 64 : 1;
    constexpr int HS   = 264;
    __shared__ unsigned short S[64 * HS];

    const int t    = threadIdx.x;
    const int lane = t & 63;
    const int wq   = t >> 6;
    const int r0   = blockIdx.x * 64;
    const int lm   = lane & 15;
    const int lq   = lane >> 4;
    const int kq   = lq * 8;

    int gr = r0 + wq * 16 + lm;
    if (gr >= N) gr = N - 1;
    const unsigned short* gA = A + (size_t)gr * K + kq;

    const unsigned short* w1b = Wq1 + (size_t)(wq * NCT1) * 512 + (size_t)lane * 8;
    h8 wv[NCT1], wvn[NCT1];
#pragma unroll
    for (int ct = 0; ct < NCT1; ++ct)
        wv[ct] = *(const h8*)(w1b + ct * 512);
#pragma unroll
    for (int c = 0; c < NCH1; ++c)
        gl_lds16(gA + c * 32, S + c * 2048 + wq * 512);
    __syncthreads();

    f4 acc[RT][NCT1];
#pragma unroll
    for (int rt = 0; rt < RT; ++rt)
#pragma unroll
        for (int ct = 0; ct < NCT1; ++ct) acc[rt][ct] = (f4){0.f, 0.f, 0.f, 0.f};

#pragma unroll
    for (int c = 0; c < NCH1; ++c) {
        if (c + 1 < NCH1) {
#pragma unroll
            for (int ct = 0; ct < NCT1; ++ct)
                wvn[ct] = *(const h8*)(w1b + ((size_t)(c + 1) * (MH / 16) + ct) * 512);
        }
        const unsigned short* ab = S + c * 2048;
        h8 ah[RT];
#pragma unroll
        for (int rt = 0; rt < RT; ++rt)
            ah[rt] = *(const h8*)(ab + rt * 512 + lane * 8);
#pragma unroll
        for (int ct = 0; ct < NCT1; ++ct)
#pragma unroll
            for (int rt = 0; rt < RT; ++rt)
                acc[rt][ct] = __builtin_amdgcn_mfma_f32_16x16x32_f16(ah[rt], wv[ct], acc[rt][ct], 0, 0, 0);
        if (c + 1 < NCH1) {
#pragma unroll
            for (int ct = 0; ct < NCT1; ++ct) wv[ct] = wvn[ct];
        }
    }
    __syncthreads();

#pragma unroll
    for (int ct = 0; ct < NCT1; ++ct) {
        const int col = wq * 64 + ct * 16 + lm;
        const float bv = b1[col];
#pragma unroll
        for (int rt = 0; rt < RT; ++rt) {
#pragma unroll
            for (int reg = 0; reg < 4; ++reg) {
                int rrow = rt * 16 + lq * 4 + reg;
                float v = acc[rt][ct][reg] + bv;
                v = v > 0.f ? v : 0.f;
                S[rrow * HS + col] = f2h(v);
            }
        }
    }

    const unsigned short* w2b = Wq2 + (size_t)(wq * NCT2) * 512 + (size_t)lane * 8;
    h8 wv2[NCT2], wv2n[NCT2];
#pragma unroll
    for (int ct = 0; ct < NCT2; ++ct)
        wv2[ct] = *(const h8*)(w2b + ct * 512);
    __syncthreads();

    f4 acc2[RT][NCT2];
#pragma unroll
    for (int rt = 0; rt < RT; ++rt)
#pragma unroll
        for (int ct = 0; ct < NCT2; ++ct) acc2[rt][ct] = (f4){0.f, 0.f, 0.f, 0.f};

#pragma unroll
    for (int c = 0; c < NCH2; ++c) {
        if (c + 1 < NCH2) {
#pragma unroll
            for (int ct = 0; ct < NCT2; ++ct)
                wv2n[ct] = *(const h8*)(w2b + ((size_t)(c + 1) * (MO / 16) + ct) * 512);
        }
        const int kk = c * 32 + kq;
        h8 hh[RT];
#pragma unroll
        for (int rt = 0; rt < RT; ++rt)
            hh[rt] = *(const h8*)(S + (rt * 16 + lm) * HS + kk);
#pragma unroll
        for (int ct = 0; ct < NCT2; ++ct)
#pragma unroll
            for (int rt = 0; rt < RT; ++rt)
                acc2[rt][ct] = __builtin_amdgcn_mfma_f32_16x16x32_f16(hh[rt], wv2[ct], acc2[rt][ct], 0, 0, 0);
        if (c + 1 < NCH2) {
#pragma unroll
            for (int ct = 0; ct < NCT2; ++ct) wv2[ct] = wv2n[ct];
        }
    }

#pragma unroll
    for (int ct = 0; ct < NCT2; ++ct) {
        const int col = wq * (MO / 4) + ct * 16 + lm;
        const float bv = b2[col];
#pragma unroll
        for (int rt = 0; rt < RT; ++rt) {
#pragma unroll
            for (int reg = 0; reg < 4; ++reg) {
                int n = r0 + rt * 16 + lq * 4 + reg;
                if (n < N)
                    Cv[(size_t)n * MO + col] = acc2[rt][ct][reg] + bv;
            }
        }
    }
}

extern "C" void kernel_launch(void* const* d_in, const int* in_sizes, int n_in,
                              void* d_out, int out_size, void* d_ws, size_t ws_size,
                              hipStream_t stream) {
    const float* x    = (const float*)d_in[0];
    const int*   row  = (const int*)d_in[1];
    const int*   col  = (const int*)d_in[2];
    const float* vals = (const float*)d_in[3];
    const float* eps0 = (const float*)d_in[4];
    const float* W1a  = (const float*)d_in[5];
    const float* b1a  = (const float*)d_in[6];
    const float* W2a  = (const float*)d_in[7];
    const float* b2a  = (const float*)d_in[8];
    const float* eps1 = (const float*)d_in[9];
    const float* W1b  = (const float*)d_in[10];
    const float* b1b  = (const float*)d_in[11];
    const float* W2b  = (const float*)d_in[12];
    const float* b2b  = (const float*)d_in[13];
    const float* Wf1  = (const float*)d_in[14];
    const float* bf1  = (const float*)d_in[15];
    const float* Wf2  = (const float*)d_in[16];
    const float* bf2  = (const float*)d_in[17];
    float* out = (float*)d_out;

    const int N = in_sizes[0] / 128;  // 100000
    const int E = in_sizes[1];        // 1600000

    char* w = (char*)d_ws;
    auto alloc = [&](size_t bytes) -> void* {
        void* p = (void*)w;
        w += (bytes + 255) & ~(size_t)255;
        return p;
    };
    unsigned short* Hb1    = (unsigned short*)alloc((size_t)N * 256 * 2); // conv-A out
    unsigned short* Hb2    = (unsigned short*)alloc((size_t)N * 256 * 2); // conv-B out
    unsigned short* xh     = (unsigned short*)alloc((size_t)N * 128 * 2); // fp16 input copy
    int*            cnt    = (int*)alloc((size_t)N * 4);
    int*            basep  = (int*)alloc((size_t)(N + 1) * 4);
    int*            cursor = (int*)alloc((size_t)N * 4);
    int*            part   = (int*)alloc(1024);
    int2*           edges  = (int2*)alloc((size_t)E * 8);
    unsigned short* Wq1a = (unsigned short*)alloc((size_t)128 * 256 * 2);
    unsigned short* Wq2a = (unsigned short*)alloc((size_t)256 * 256 * 2);
    unsigned short* Wq1b = (unsigned short*)alloc((size_t)256 * 256 * 2);
    unsigned short* Wq2b = (unsigned short*)alloc((size_t)256 * 256 * 2);
    unsigned short* Wqf1 = (unsigned short*)alloc((size_t)256 * 256 * 2);
    unsigned short* Wqf2 = (unsigned short*)alloc((size_t)256 * 64 * 2);

    // ---- CSR build ----
    k_zero<<<(N + 255) / 256, 256, 0, stream>>>(cnt, N);
    k_hist<<<(E + 255) / 256, 256, 0, stream>>>(row, cnt, E);
    int nb = (N + 1023) / 1024;  // 98
    k_scan1<<<nb, 256, 0, stream>>>(cnt, basep, part, N);
    k_scan2<<<1, 256, 0, stream>>>(part, nb);
    k_scan3<<<(N + 255) / 256, 256, 0, stream>>>(basep, cursor, part, N, E);
    k_scatter<<<(E + 255) / 256, 256, 0, stream>>>(row, col, vals, cursor, edges, E);

    // ---- weight fp16 swizzle, input fp16 cast ----
    k_wprep_all<<<1216, 256, 0, stream>>>(W1a, Wq1a, W2a, Wq2a, W1b, Wq1b,
                                          W2b, Wq2b, Wf1, Wqf1, Wf2, Wqf2);
    k_cvt<<<(N * 128 / 4 + 255) / 256, 256, 0, stream>>>(x, xh, N * 128);

    const int grid = (N + 63) / 64;

    // ---- conv A (fused spmm + MLP) ----
    k_conv<128><<<grid, 256, 0, stream>>>(basep, edges, xh, Wq1a, b1a,
                                          Wq2a, b2a, Hb1, eps0, N);
    // ---- conv B (fused spmm + MLP) ----
    k_conv<256><<<grid, 256, 0, stream>>>(basep, edges, Hb1, Wq1b, b1b,
                                          Wq2b, b2b, Hb2, eps1, N);
    // ---- head ----
    k_mlp<256, 64><<<grid, 256, 0, stream>>>(Hb2, Wqf1, bf1, Wqf2, bf2, out, N);
}